// Round 4
// baseline (475.995 us; speedup 1.0000x reference)
//
#include <hip/hip_runtime.h>
#include <math.h>

#define NN 50000
#define EE 800000
#define ET (EE + NN)   // 850000 edges incl. self-loops
#define C  64
#define NBLK 49        // ceil(NN/1024) scan blocks
#define NCHUNK 831     // ceil(ET/1024) edge chunks
#define ZBLK 463       // zeroing blocks appended to scan_partial

typedef __attribute__((ext_vector_type(8))) _Float16 f16x8;
typedef __attribute__((ext_vector_type(4))) _Float16 f16x4;
typedef __attribute__((ext_vector_type(2))) _Float16 f16x2;
typedef __attribute__((ext_vector_type(4))) float f32x4;

__device__ __forceinline__ f16x2 pk2(float a, float b) {
  return __builtin_bit_cast(f16x2, __builtin_amdgcn_cvt_pkrtz(a, b));
}
__device__ __forceinline__ f16x4 pk4(float a, float b, float c, float d) {
  return __builtin_shufflevector(pk2(a, b), pk2(c, d), 0, 1, 2, 3);
}
__device__ __forceinline__ f16x8 pk8(const float* y) {
  const f16x4 lo = pk4(y[0], y[1], y[2], y[3]);
  const f16x4 hi = pk4(y[4], y[5], y[6], y[7]);
  return __builtin_shufflevector(lo, hi, 0, 1, 2, 3, 4, 5, 6, 7);
}

// ---------------- padded (stride-72) LDS helpers: node_proj / out_proj ------
__device__ __forceinline__ f16x8 frag_ldh(const _Float16* base, int row,
                                          int kofs) {
  return *(const f16x8*)(base + row * 72 + kofs);
}
__device__ __forceinline__ void stage_w(_Float16* __restrict__ dst,
                                        const _Float16* __restrict__ src16,
                                        int tid) {
  const f16x8* src = (const f16x8*)(src16 + tid * 16);
  _Float16* d = dst + (tid >> 2) * 72 + (tid & 3) * 16;
  ((f16x8*)d)[0] = src[0];
  ((f16x8*)d)[1] = src[1];
}

// ---------------- dense (stride-64) XOR-swizzled LDS helpers: edge_pass -----
// phys byte = row*128 + (colbyte ^ ((row&7)<<4)); bijective per 16B block,
// preserves 16B/8B alignment; 2-way max bank aliasing (free on CDNA4).
__device__ __forceinline__ int swzb(int row, int colbyte) {
  return row * 128 + (colbyte ^ ((row & 7) << 4));
}
__device__ __forceinline__ f16x8 frag_lds(const _Float16* base, int row,
                                          int kofs) {
  return *(const f16x8*)((const char*)base + swzb(row, kofs * 2));
}
__device__ __forceinline__ void stage_ws(_Float16* __restrict__ dst,
                                         const _Float16* __restrict__ src16,
                                         int tid) {
  const f16x8* src = (const f16x8*)(src16 + tid * 16);
  const int row = tid >> 2;
  const int c0 = (tid & 3) * 32;  // bytes
  *(f16x8*)((char*)dst + swzb(row, c0)) = src[0];
  *(f16x8*)((char*)dst + swzb(row, c0 + 16)) = src[1];
}

// ---------------------------------------------------------------------------
// prep: convert 8 weight matrices f32 -> f16 (blocks 0..7) + zero cnt shards
// order: W_in, W_lin, W_src, W_dst, att_w1, att_w2, pos_w2, W_out
// att_w2 is pre-scaled by log2(e) so edge_pass can use exp2 directly.
// ---------------------------------------------------------------------------
__global__ __launch_bounds__(256) void prep_kernel(
    const float* __restrict__ W_in, const float* __restrict__ W_lin,
    const float* __restrict__ W_src, const float* __restrict__ W_dst,
    const float* __restrict__ att_w1, const float* __restrict__ att_w2,
    const float* __restrict__ pos_w2, const float* __restrict__ W_out,
    _Float16* __restrict__ w16, int* __restrict__ cnt2) {
  if (blockIdx.x < 8) {
    const float* Ws[8] = {W_in, W_lin, W_src, W_dst, att_w1, att_w2, pos_w2,
                          W_out};
    const float* src = Ws[blockIdx.x];
    _Float16* dst = w16 + blockIdx.x * 4096;
    const float sc = (blockIdx.x == 5) ? 1.44269504088896340736f : 1.0f;
#pragma unroll
    for (int i = threadIdx.x * 4; i < 4096; i += 1024) {
      const float4 w = *(const float4*)(src + i);
      *(f16x4*)(dst + i) = pk4(w.x * sc, w.y * sc, w.z * sc, w.w * sc);
    }
  }
  // zero all 8 counter shards (8*NN ints = 2*NN int4) across 64 blocks
  int4* cz = (int4*)cnt2;
#pragma unroll 1
  for (int i = blockIdx.x * 256 + threadIdx.x; i < 2 * NN; i += 64 * 256)
    cz[i] = make_int4(0, 0, 0, 0);
}

// ---------------------------------------------------------------------------
// Scan over sharded counters; extra blocks zero num/den.
// ---------------------------------------------------------------------------
__global__ __launch_bounds__(256) void scan_partial(const int* __restrict__ cnt2,
                                                    int* __restrict__ bsum,
                                                    float* __restrict__ zeroreg) {
  const int t = threadIdx.x;
  if (blockIdx.x >= NBLK) {
    const int zb = blockIdx.x - NBLK;
    float4* dst = (float4*)zeroreg;
    const int total4 = 2 * NN * 64 / 4;
    const float4 z = make_float4(0.f, 0.f, 0.f, 0.f);
#pragma unroll 1
    for (int i = zb * 256 + t; i < total4; i += ZBLK * 256) dst[i] = z;
    return;
  }
  __shared__ int ws[4];
  const int base = blockIdx.x * 1024 + t * 4;
  int s = 0;
  if (base + 3 < NN) {
#pragma unroll
    for (int sh = 0; sh < 8; ++sh) {
      const int4 v = *(const int4*)(cnt2 + sh * NN + base);
      s += v.x + v.y + v.z + v.w;
    }
  } else {
#pragma unroll
    for (int i = 0; i < 4; ++i)
      if (base + i < NN)
#pragma unroll
        for (int sh = 0; sh < 8; ++sh) s += cnt2[sh * NN + base + i];
  }
#pragma unroll
  for (int off = 32; off; off >>= 1) s += __shfl_down(s, off, 64);
  if ((t & 63) == 0) ws[t >> 6] = s;
  __syncthreads();
  if (t == 0) bsum[blockIdx.x] = ws[0] + ws[1] + ws[2] + ws[3];
}

__global__ __launch_bounds__(256) void scan_final(const int* __restrict__ cnt2,
                                                  const int* __restrict__ bsum,
                                                  int* __restrict__ curs2) {
  __shared__ int tsum[256];
  __shared__ int sblk[64];
  const int t = threadIdx.x;
  if (t < 64) {
    const int mine = (t < NBLK) ? bsum[t] : 0;
    int v = mine;
#pragma unroll
    for (int off = 1; off < 64; off <<= 1) {
      const int u = __shfl_up(v, off, 64);
      if (t >= off) v += u;
    }
    sblk[t] = v - mine;
  }
  const int base = blockIdx.x * 1024 + t * 4;
  int c2[8][4];
  int v[4] = {0, 0, 0, 0};
  if (base + 3 < NN) {
#pragma unroll
    for (int sh = 0; sh < 8; ++sh) {
      const int4 x = *(const int4*)(cnt2 + sh * NN + base);
      c2[sh][0] = x.x; c2[sh][1] = x.y; c2[sh][2] = x.z; c2[sh][3] = x.w;
      v[0] += x.x; v[1] += x.y; v[2] += x.z; v[3] += x.w;
    }
  } else {
#pragma unroll
    for (int sh = 0; sh < 8; ++sh)
#pragma unroll
      for (int i = 0; i < 4; ++i) {
        const int c = (base + i < NN) ? cnt2[sh * NN + base + i] : 0;
        c2[sh][i] = c;
        v[i] += c;
      }
  }
  const int s = v[0] + v[1] + v[2] + v[3];
  tsum[t] = s;
  __syncthreads();
  for (int off = 1; off < 256; off <<= 1) {
    const int u = (t >= off) ? tsum[t - off] : 0;
    __syncthreads();
    tsum[t] += u;
    __syncthreads();
  }
  int ex = sblk[blockIdx.x] + tsum[t] - s;
  int offs[8][4];
#pragma unroll
  for (int i = 0; i < 4; ++i) {
    int run = ex;
#pragma unroll
    for (int sh = 0; sh < 8; ++sh) {
      offs[sh][i] = run;
      run += c2[sh][i];
    }
    ex += v[i];
  }
  if (base + 3 < NN) {
#pragma unroll
    for (int sh = 0; sh < 8; ++sh)
      *(int4*)(curs2 + sh * NN + base) =
          make_int4(offs[sh][0], offs[sh][1], offs[sh][2], offs[sh][3]);
  } else {
#pragma unroll
    for (int sh = 0; sh < 8; ++sh)
#pragma unroll
      for (int i = 0; i < 4; ++i)
        if (base + i < NN) curs2[sh * NN + base + i] = offs[sh][i];
  }
}

// scatter: block b owns edge chunk b (1024 edges); shard = b&7 (XCD-aligned).
__global__ __launch_bounds__(256) void scatter_kernel(const int* __restrict__ ei,
                                                      int* __restrict__ curs2,
                                                      int2* __restrict__ srt) {
  const int chunk = blockIdx.x;
  int* cs = curs2 + (chunk & 7) * NN;
  const int e0 = chunk * 1024 + threadIdx.x * 4;
  if (e0 >= ET) return;
  int s[4], d[4];
  if (e0 + 3 < EE) {
    const int4 sv = *(const int4*)(ei + e0);
    const int4 dv = *(const int4*)(ei + EE + e0);
    s[0] = sv.x; s[1] = sv.y; s[2] = sv.z; s[3] = sv.w;
    d[0] = dv.x; d[1] = dv.y; d[2] = dv.z; d[3] = dv.w;
  } else {
#pragma unroll
    for (int i = 0; i < 4; ++i) {
      const int e = e0 + i;
      if (e < EE) {
        s[i] = ei[e];
        d[i] = ei[EE + e];
      } else if (e < ET) {
        s[i] = d[i] = e - EE;
      } else {
        s[i] = d[i] = -1;
      }
    }
  }
#pragma unroll
  for (int i = 0; i < 4; ++i) {
    if (d[i] >= 0) {
      const int p = atomicAdd(&cs[d[i]], 1);
      srt[p] = make_int2(s[i], d[i]);
    }
  }
}

// ---------------------------------------------------------------------------
// Kernel A: fused sharded histogram + node projections (MFMA f16).
// ---------------------------------------------------------------------------
__global__ __launch_bounds__(256, 3) void node_proj(
    const float* __restrict__ x, const float* __restrict__ b_in,
    const _Float16* __restrict__ w16, const int* __restrict__ ei,
    int* __restrict__ cnt2, _Float16* __restrict__ vh,
    _Float16* __restrict__ kh, _Float16* __restrict__ qh) {
  __shared__ __align__(16) _Float16 wlds[4 * 4608];  // W_in|W_lin|W_src|W_dst
  __shared__ __align__(16) _Float16 hlds[4608];
  __shared__ float biasv[64];

  const int tid = threadIdx.x;
  const int nb = blockIdx.x * 64;
  const int l15 = tid & 15;
  const int quad = (tid >> 4) & 3;
  const int wband = tid >> 6;
  const int nloc = wband * 16 + l15;
  const int gn = nb + nloc;

  // sharded fire-and-forget histogram; chunk c = edges [c*1024,(c+1)*1024)
#pragma unroll 1
  for (int chunk = blockIdx.x; chunk < NCHUNK; chunk += gridDim.x) {
    int* cs = cnt2 + (chunk & 7) * NN;
    const int e0 = chunk * 1024 + tid * 4;
    if (e0 < ET) {
      int d[4];
      if (e0 + 3 < EE) {
        const int4 dv = *(const int4*)(ei + EE + e0);
        d[0] = dv.x; d[1] = dv.y; d[2] = dv.z; d[3] = dv.w;
      } else {
#pragma unroll
        for (int i = 0; i < 4; ++i) {
          const int e = e0 + i;
          d[i] = (e < EE) ? ei[EE + e] : ((e < ET) ? e - EE : -1);
        }
      }
#pragma unroll
      for (int i = 0; i < 4; ++i)
        if (d[i] >= 0) atomicAdd(&cs[d[i]], 1);
    }
  }

#pragma unroll
  for (int w = 0; w < 4; ++w) stage_w(wlds + w * 4608, w16 + w * 4096, tid);
  if (tid < 64) biasv[tid] = b_in[tid];

  // B-frag from x (f32 -> f16)
  f16x8 bfrag[2];
#pragma unroll
  for (int ks = 0; ks < 2; ++ks) {
    float y[8] = {0.f, 0.f, 0.f, 0.f, 0.f, 0.f, 0.f, 0.f};
    if (gn < NN) {
      const float4 a = *(const float4*)(x + (size_t)gn * 64 + ks * 32 + quad * 8);
      const float4 b = *(const float4*)(x + (size_t)gn * 64 + ks * 32 + quad * 8 + 4);
      y[0] = a.x; y[1] = a.y; y[2] = a.z; y[3] = a.w;
      y[4] = b.x; y[5] = b.y; y[6] = b.z; y[7] = b.w;
    }
    bfrag[ks] = pk8(y);
  }
  __syncthreads();  // B0

  // GEMM1: h = relu(W_in . x^T + b) -> hlds rows [n][o] f16
#pragma unroll
  for (int t = 0; t < 4; ++t) {
    f32x4 acc = {0.f, 0.f, 0.f, 0.f};
#pragma unroll
    for (int ks = 0; ks < 2; ++ks) {
      const f16x8 af = frag_ldh(wlds, t * 16 + l15, ks * 32 + quad * 8);
      acc = __builtin_amdgcn_mfma_f32_16x16x32_f16(af, bfrag[ks], acc, 0, 0, 0);
    }
    const int hb = t * 16 + quad * 4;
    *(f16x4*)(hlds + nloc * 72 + hb) =
        pk4(fmaxf(acc[0] + biasv[hb + 0], 0.f), fmaxf(acc[1] + biasv[hb + 1], 0.f),
            fmaxf(acc[2] + biasv[hb + 2], 0.f), fmaxf(acc[3] + biasv[hb + 3], 0.f));
  }
  __syncthreads();  // B1

  f16x8 hfrag[2];
#pragma unroll
  for (int ks = 0; ks < 2; ++ks)
    hfrag[ks] = frag_ldh(hlds, nloc, ks * 32 + quad * 8);

  _Float16* outs[3] = {vh, kh, qh};
#pragma unroll
  for (int p = 0; p < 3; ++p) {
    const _Float16* W = wlds + (p + 1) * 4608;
#pragma unroll
    for (int t = 0; t < 4; ++t) {
      f32x4 acc = {0.f, 0.f, 0.f, 0.f};
#pragma unroll
      for (int ks = 0; ks < 2; ++ks) {
        const f16x8 af = frag_ldh(W, t * 16 + l15, ks * 32 + quad * 8);
        acc = __builtin_amdgcn_mfma_f32_16x16x32_f16(af, hfrag[ks], acc, 0, 0, 0);
      }
      if (gn < NN) {
        *(f16x4*)(outs[p] + (size_t)gn * 64 + t * 16 + quad * 4) =
            pk4(acc[0], acc[1], acc[2], acc[3]);
      }
    }
  }
}

// ---------------------------------------------------------------------------
// Kernel B: MFMA (f16) edge pass, 64 edges / 256 threads.
// Swapped-operand GEMM2/GEMM3: mfma(A=h-rows(edges), B=W-rows(channels))
// gives output [edge=quad*4+reg][ch=tc*16+l15] per lane -> the softmax/
// message/segmented-reduce axis (edges) is REGISTER-LOCAL. No pairb LDS
// transpose, no serial phase-6 scan; per-lane 4-edge in-register segmented
// reduce + boundary atomics. 3 barriers, LDS 25.9KB -> 6 blocks/CU.
// ---------------------------------------------------------------------------
__global__ __launch_bounds__(256, 6) void edge_pass(
    const int2* __restrict__ srt, const float* __restrict__ pos,
    const _Float16* __restrict__ vh, const _Float16* __restrict__ kh,
    const _Float16* __restrict__ qh, const _Float16* __restrict__ w16,
    const float* __restrict__ att_b1, const float* __restrict__ att_b2,
    const float* __restrict__ pos_w1, const float* __restrict__ pos_b1,
    const float* __restrict__ pos_b2, float* __restrict__ num,
    float* __restrict__ den) {
  __shared__ __align__(16) _Float16 smem[12288];  // W1(->PW2)|W2|HP dense
  __shared__ __align__(16) float posw1T[3 * 64];
  __shared__ float b1s[64], b2s[64], pb1s[64], pb2s[64];
  __shared__ int dsts[64];
  __shared__ int srcs[64];

  _Float16* W1 = smem;             // W1, then PW2 after B1/B2
  _Float16* W2 = smem + 4096;
  _Float16* HP = smem + 8192;      // h1 (64 x 64)

  const int tid = threadIdx.x;
  const int eb = blockIdx.x * 64;
  const int l15 = tid & 15;
  const int quad = (tid >> 4) & 3;
  const int wband = tid >> 6;
  const int eloc = wband * 16 + l15;

  // ---- phase 0a: per-lane edge read + B-frag: ad = q[dst]-k[src] (f16)
  int s_mine, d_mine;
  f16x8 bfrag[2];
  float dp0, dp1, dp2;
  {
    const int e = eb + eloc;
    int2 sd = make_int2(0, 0);
    int valid_d = -1;
    if (e < ET) {
      sd = srt[e];
      valid_d = sd.y;
    }
    s_mine = sd.x;
    d_mine = sd.y;
    if (quad == 0) {
      dsts[eloc] = valid_d;
      srcs[eloc] = sd.x;
    }
#pragma unroll
    for (int ks = 0; ks < 2; ++ks) {
      const f16x8 qv =
          *(const f16x8*)(qh + (size_t)d_mine * 64 + ks * 32 + quad * 8);
      const f16x8 kv =
          *(const f16x8*)(kh + (size_t)s_mine * 64 + ks * 32 + quad * 8);
      bfrag[ks] = qv - kv;
    }
    dp0 = pos[(size_t)d_mine * 3 + 0] - pos[(size_t)s_mine * 3 + 0];
    dp1 = pos[(size_t)d_mine * 3 + 1] - pos[(size_t)s_mine * 3 + 1];
    dp2 = pos[(size_t)d_mine * 3 + 2] - pos[(size_t)s_mine * 3 + 2];
  }

  // ---- phase 0b: stage W1, W2 (f16), biases, posw1T
  stage_ws(W1, w16 + 4 * 4096, tid);
  stage_ws(W2, w16 + 5 * 4096, tid);
  if (tid < 64) {
    b1s[tid] = att_b1[tid];
    b2s[tid] = att_b2[tid] * 1.44269504088896340736f;  // W2 prescaled in prep
    pb1s[tid] = pos_b1[tid];
    pb2s[tid] = pos_b2[tid];
    posw1T[0 * 64 + tid] = pos_w1[tid * 3 + 0];
    posw1T[1 * 64 + tid] = pos_w1[tid * 3 + 1];
    posw1T[2 * 64 + tid] = pos_w1[tid * 3 + 2];
  }
  __syncthreads();  // B0

  // ---- per-lane run metadata for edges quad*4+r of own band, and the v
  // gather BY CHANNEL: vv[tc*4+r] = v[src(edge)][tc*16+l15]. 16 ushort loads
  // per lane (each (quad,tc) 16-lane group reads 32 contiguous bytes);
  // issued here so latency hides under GEMM1/GEMM2.
  int d4[4], s4[4];
#pragma unroll
  for (int r = 0; r < 4; ++r) {
    d4[r] = dsts[wband * 16 + quad * 4 + r];
    s4[r] = srcs[wband * 16 + quad * 4 + r];
  }
  _Float16 vvh[16];
#pragma unroll
  for (int r = 0; r < 4; ++r) {
    const int sr = (d4[r] >= 0) ? s4[r] : 0;
    const _Float16* vp = vh + (size_t)sr * 64 + l15;
#pragma unroll
    for (int tc = 0; tc < 4; ++tc) vvh[tc * 4 + r] = vp[tc * 16];
  }
  float b2v[4], pb2v[4];
#pragma unroll
  for (int tc = 0; tc < 4; ++tc) {
    b2v[tc] = b2s[tc * 16 + l15];
    pb2v[tc] = pb2s[tc * 16 + l15];
  }

  // ---- GEMM1: h1 = relu(W1 . ad^T + b1) -> HP rows [e][h] f16 (wave-private)
#pragma unroll
  for (int t = 0; t < 4; ++t) {
    f32x4 acc = {0.f, 0.f, 0.f, 0.f};
#pragma unroll
    for (int ks = 0; ks < 2; ++ks) {
      const f16x8 af = frag_lds(W1, t * 16 + l15, ks * 32 + quad * 8);
      acc = __builtin_amdgcn_mfma_f32_16x16x32_f16(af, bfrag[ks], acc, 0, 0, 0);
    }
    const int hb = t * 16 + quad * 4;
    *(f16x4*)((char*)HP + swzb(eloc, hb * 2)) =
        pk4(fmaxf(acc[0] + b1s[hb + 0], 0.f), fmaxf(acc[1] + b1s[hb + 1], 0.f),
            fmaxf(acc[2] + b1s[hb + 2], 0.f), fmaxf(acc[3] + b1s[hb + 3], 0.f));
  }

  // ---- hp in registers (k=3 pos-MLP layer 1 for this lane's 16 k-values)
  f16x8 hpfrag[2];
#pragma unroll
  for (int ks = 0; ks < 2; ++ks) {
    float hv[8];
#pragma unroll
    for (int j = 0; j < 8; ++j) {
      const int i = ks * 32 + quad * 8 + j;
      float h = pb1s[i];
      h = fmaf(dp0, posw1T[i], h);
      h = fmaf(dp1, posw1T[64 + i], h);
      h = fmaf(dp2, posw1T[128 + i], h);
      hv[j] = fmaxf(h, 0.f);
    }
    hpfrag[ks] = pk8(hv);
  }

  // ---- GEMM2 (swapped): alpha^T = h1 . W2^T; lane gets [edge=quad*4+r][ch=
  // tc*16+l15]. ex = exp2(relu(alpha'+b2')) (prescaled by log2e in prep).
  float exq[16];
  {
    f16x8 hfrag[2];
#pragma unroll
    for (int ks = 0; ks < 2; ++ks)
      hfrag[ks] = frag_lds(HP, eloc, ks * 32 + quad * 8);
#pragma unroll
    for (int tc = 0; tc < 4; ++tc) {
      f32x4 acc = {0.f, 0.f, 0.f, 0.f};
#pragma unroll
      for (int ks = 0; ks < 2; ++ks) {
        const f16x8 bw = frag_lds(W2, tc * 16 + l15, ks * 32 + quad * 8);
        acc = __builtin_amdgcn_mfma_f32_16x16x32_f16(hfrag[ks], bw, acc, 0, 0, 0);
      }
#pragma unroll
      for (int r = 0; r < 4; ++r)
        exq[tc * 4 + r] = __builtin_exp2f(fmaxf(acc[r] + b2v[tc], 0.f));
    }
  }
  __syncthreads();  // B1: all waves done with W1, W2, h1

  stage_ws(W1, w16 + 6 * 4096, tid);  // PW2 over W1 region
  __syncthreads();  // B2: PW2 visible

  // ---- GEMM3 (swapped) + fused per-lane segmented reduce.
  // del^T = hp . PW2^T -> [edge=quad*4+r][ch=tc*16+l15]; msg = ex*(v+del);
  // 4 sorted edges per lane: in-register scan, atomic per run boundary.
#pragma unroll
  for (int tc = 0; tc < 4; ++tc) {
    f32x4 acc = {0.f, 0.f, 0.f, 0.f};
#pragma unroll
    for (int ks = 0; ks < 2; ++ks) {
      const f16x8 bw = frag_lds(W1, tc * 16 + l15, ks * 32 + quad * 8);
      acc = __builtin_amdgcn_mfma_f32_16x16x32_f16(hpfrag[ks], bw, acc, 0, 0, 0);
    }
    const int ch = tc * 16 + l15;
    float m4[4], e4[4];
#pragma unroll
    for (int r = 0; r < 4; ++r) {
      const float del = fmaxf(acc[r] + pb2v[tc], 0.f);
      e4[r] = exq[tc * 4 + r];
      m4[r] = e4[r] * ((float)vvh[tc * 4 + r] + del);
    }
    float am = 0.f, ae = 0.f;
    int cur = d4[0];
#pragma unroll
    for (int r = 0; r < 4; ++r) {
      if (d4[r] != cur) {
        if (cur >= 0) {
          unsafeAtomicAdd(num + (size_t)cur * 64 + ch, am);
          unsafeAtomicAdd(den + (size_t)cur * 64 + ch, ae);
        }
        am = 0.f;
        ae = 0.f;
        cur = d4[r];
      }
      if (d4[r] >= 0) {
        am += m4[r];
        ae += e4[r];
      }
    }
    if (cur >= 0) {
      unsafeAtomicAdd(num + (size_t)cur * 64 + ch, am);
      unsafeAtomicAdd(den + (size_t)cur * 64 + ch, ae);
    }
  }
}

// ---------------------------------------------------------------------------
// Kernel C: out = relu((num/(den+1e-16)) @ W_out.T + b_out), MFMA f16.
// ---------------------------------------------------------------------------
__global__ __launch_bounds__(256, 4) void out_proj(
    const float* __restrict__ num, const float* __restrict__ den,
    const _Float16* __restrict__ w16, const float* __restrict__ b_out,
    float* __restrict__ out) {
  __shared__ __align__(16) _Float16 wlds[4608];
  __shared__ float biasv[64];

  const int tid = threadIdx.x;
  const int nb = blockIdx.x * 64;
  const int l15 = tid & 15;
  const int quad = (tid >> 4) & 3;
  const int wband = tid >> 6;
  const int gn = nb + wband * 16 + l15;

  stage_w(wlds, w16 + 7 * 4096, tid);
  if (tid < 64) biasv[tid] = b_out[tid];

  f16x8 bfrag[2];
#pragma unroll
  for (int ks = 0; ks < 2; ++ks) {
    float y[8] = {0.f, 0.f, 0.f, 0.f, 0.f, 0.f, 0.f, 0.f};
    if (gn < NN) {
      const size_t base = (size_t)gn * 64 + ks * 32 + quad * 8;
      const float4 n0 = *(const float4*)(num + base);
      const float4 n1 = *(const float4*)(num + base + 4);
      const float4 d0 = *(const float4*)(den + base);
      const float4 d1 = *(const float4*)(den + base + 4);
      y[0] = n0.x / (d0.x + 1e-16f); y[1] = n0.y / (d0.y + 1e-16f);
      y[2] = n0.z / (d0.z + 1e-16f); y[3] = n0.w / (d0.w + 1e-16f);
      y[4] = n1.x / (d1.x + 1e-16f); y[5] = n1.y / (d1.y + 1e-16f);
      y[6] = n1.z / (d1.z + 1e-16f); y[7] = n1.w / (d1.w + 1e-16f);
    }
    bfrag[ks] = pk8(y);
  }
  __syncthreads();

#pragma unroll
  for (int t = 0; t < 4; ++t) {
    f32x4 acc = {0.f, 0.f, 0.f, 0.f};
#pragma unroll
    for (int ks = 0; ks < 2; ++ks) {
      const f16x8 af = frag_ldh(wlds, t * 16 + l15, ks * 32 + quad * 8);
      acc = __builtin_amdgcn_mfma_f32_16x16x32_f16(af, bfrag[ks], acc, 0, 0, 0);
    }
    if (gn < NN) {
      const int ob = t * 16 + quad * 4;
      float4 r;
      r.x = fmaxf(acc[0] + biasv[ob + 0], 0.f);
      r.y = fmaxf(acc[1] + biasv[ob + 1], 0.f);
      r.z = fmaxf(acc[2] + biasv[ob + 2], 0.f);
      r.w = fmaxf(acc[3] + biasv[ob + 3], 0.f);
      *(float4*)(out + (size_t)gn * 64 + ob) = r;
    }
  }
}

extern "C" void kernel_launch(void* const* d_in, const int* in_sizes, int n_in,
                              void* d_out, int out_size, void* d_ws,
                              size_t ws_size, hipStream_t stream) {
  const float* x      = (const float*)d_in[0];
  const float* pos    = (const float*)d_in[1];
  const int*   ei     = (const int*)d_in[2];
  const float* W_in   = (const float*)d_in[3];
  const float* b_in   = (const float*)d_in[4];
  const float* W_out  = (const float*)d_in[5];
  const float* b_out  = (const float*)d_in[6];
  const float* W_lin  = (const float*)d_in[7];
  const float* W_src  = (const float*)d_in[8];
  const float* W_dst  = (const float*)d_in[9];
  const float* pos_w1 = (const float*)d_in[10];
  const float* pos_b1 = (const float*)d_in[11];
  const float* pos_w2 = (const float*)d_in[12];
  const float* pos_b2 = (const float*)d_in[13];
  const float* att_w1 = (const float*)d_in[14];
  const float* att_b1 = (const float*)d_in[15];
  const float* att_w2 = (const float*)d_in[16];
  const float* att_b2 = (const float*)d_in[17];

  float* ws = (float*)d_ws;
  const size_t NC = (size_t)NN * C;
  float* num = ws;                       // NC f32
  float* den = ws + NC;                  // NC f32
  _Float16* vh = (_Float16*)(ws + 2 * NC);  // NC f16
  _Float16* kh = vh + NC;                    // NC f16
  _Float16* qh = kh + NC;                    // NC f16
  _Float16* w16 = qh + NC;                   // 8*4096 f16
  int* ib     = (int*)(w16 + 8 * 4096);
  int* cnt2   = ib;                      // 8*NN
  int* curs2  = ib + 8 * NN;             // 8*NN
  int* bsum   = ib + 16 * NN;            // NBLK
  int2* srt   = (int2*)(((uintptr_t)(bsum + NBLK) + 15) & ~(uintptr_t)15);

  const dim3 blk(256);
  prep_kernel<<<dim3(64), blk, 0, stream>>>(W_in, W_lin, W_src, W_dst, att_w1,
                                            att_w2, pos_w2, W_out, w16, cnt2);
  node_proj<<<dim3((NN + 63) / 64), blk, 0, stream>>>(x, b_in, w16, ei, cnt2,
                                                      vh, kh, qh);
  scan_partial<<<dim3(NBLK + ZBLK), blk, 0, stream>>>(cnt2, bsum, num);
  scan_final<<<dim3(NBLK), blk, 0, stream>>>(cnt2, bsum, curs2);
  scatter_kernel<<<dim3(NCHUNK), blk, 0, stream>>>(ei, curs2, srt);
  edge_pass<<<dim3((ET + 63) / 64), blk, 0, stream>>>(
      srt, pos, vh, kh, qh, w16, att_b1, att_b2, pos_w1, pos_b1, pos_b2, num,
      den);
  out_proj<<<dim3((NN + 63) / 64), blk, 0, stream>>>(num, den, w16, b_out,
                                                     (float*)d_out);
}

// Round 5
// 373.324 us; speedup vs baseline: 1.2750x; 1.2750x over previous
//
#include <hip/hip_runtime.h>
#include <math.h>

#define NN 50000
#define EE 800000
#define ET (EE + NN)   // 850000 edges incl. self-loops
#define C  64
#define NBLK 49        // ceil(NN/1024) scan blocks
#define NCHUNK 831     // ceil(ET/1024) edge chunks
#define ZBLK 463       // zeroing blocks appended to scan_partial

typedef __attribute__((ext_vector_type(8))) _Float16 f16x8;
typedef __attribute__((ext_vector_type(4))) _Float16 f16x4;
typedef __attribute__((ext_vector_type(2))) _Float16 f16x2;
typedef __attribute__((ext_vector_type(4))) float f32x4;

__device__ __forceinline__ f16x2 pk2(float a, float b) {
  return __builtin_bit_cast(f16x2, __builtin_amdgcn_cvt_pkrtz(a, b));
}
__device__ __forceinline__ f16x4 pk4(float a, float b, float c, float d) {
  return __builtin_shufflevector(pk2(a, b), pk2(c, d), 0, 1, 2, 3);
}
__device__ __forceinline__ f16x8 pk8(const float* y) {
  const f16x4 lo = pk4(y[0], y[1], y[2], y[3]);
  const f16x4 hi = pk4(y[4], y[5], y[6], y[7]);
  return __builtin_shufflevector(lo, hi, 0, 1, 2, 3, 4, 5, 6, 7);
}

// ---------------- padded (stride-72) LDS helpers: node_proj / out_proj ------
__device__ __forceinline__ f16x8 frag_ldh(const _Float16* base, int row,
                                          int kofs) {
  return *(const f16x8*)(base + row * 72 + kofs);
}
__device__ __forceinline__ void stage_w(_Float16* __restrict__ dst,
                                        const _Float16* __restrict__ src16,
                                        int tid) {
  const f16x8* src = (const f16x8*)(src16 + tid * 16);
  _Float16* d = dst + (tid >> 2) * 72 + (tid & 3) * 16;
  ((f16x8*)d)[0] = src[0];
  ((f16x8*)d)[1] = src[1];
}

// ---------------- dense (stride-64) XOR-swizzled LDS helpers: edge_pass -----
// phys byte = row*128 + (colbyte ^ ((row&7)<<4)); bijective per 16B block,
// preserves 16B/8B alignment; 2-way max bank aliasing (free on CDNA4).
__device__ __forceinline__ int swzb(int row, int colbyte) {
  return row * 128 + (colbyte ^ ((row & 7) << 4));
}
__device__ __forceinline__ f16x8 frag_lds(const _Float16* base, int row,
                                          int kofs) {
  return *(const f16x8*)((const char*)base + swzb(row, kofs * 2));
}
__device__ __forceinline__ void stage_ws(_Float16* __restrict__ dst,
                                         const _Float16* __restrict__ src16,
                                         int tid) {
  const f16x8* src = (const f16x8*)(src16 + tid * 16);
  const int row = tid >> 2;
  const int c0 = (tid & 3) * 32;  // bytes
  *(f16x8*)((char*)dst + swzb(row, c0)) = src[0];
  *(f16x8*)((char*)dst + swzb(row, c0 + 16)) = src[1];
}

// pairb swizzle: 2-way banks on BOTH write (vary e,o-quad) and read (vary o)
__device__ __forceinline__ int psl(int e, int o) {
  return (e + 2 * o + (o >> 5)) & 63;
}

// ---------------------------------------------------------------------------
// prep: convert 8 weight matrices f32 -> f16 (blocks 0..7) + zero cnt shards
// order: W_in, W_lin, W_src, W_dst, att_w1, att_w2, pos_w2, W_out
// att_w2 is pre-scaled by log2(e) so edge_pass can use exp2 directly.
// ---------------------------------------------------------------------------
__global__ __launch_bounds__(256) void prep_kernel(
    const float* __restrict__ W_in, const float* __restrict__ W_lin,
    const float* __restrict__ W_src, const float* __restrict__ W_dst,
    const float* __restrict__ att_w1, const float* __restrict__ att_w2,
    const float* __restrict__ pos_w2, const float* __restrict__ W_out,
    _Float16* __restrict__ w16, int* __restrict__ cnt2) {
  if (blockIdx.x < 8) {
    const float* Ws[8] = {W_in, W_lin, W_src, W_dst, att_w1, att_w2, pos_w2,
                          W_out};
    const float* src = Ws[blockIdx.x];
    _Float16* dst = w16 + blockIdx.x * 4096;
    const float sc = (blockIdx.x == 5) ? 1.44269504088896340736f : 1.0f;
#pragma unroll
    for (int i = threadIdx.x * 4; i < 4096; i += 1024) {
      const float4 w = *(const float4*)(src + i);
      *(f16x4*)(dst + i) = pk4(w.x * sc, w.y * sc, w.z * sc, w.w * sc);
    }
  }
  // zero all 8 counter shards (8*NN ints = 2*NN int4) across 64 blocks
  int4* cz = (int4*)cnt2;
#pragma unroll 1
  for (int i = blockIdx.x * 256 + threadIdx.x; i < 2 * NN; i += 64 * 256)
    cz[i] = make_int4(0, 0, 0, 0);
}

// ---------------------------------------------------------------------------
// Scan over sharded counters; extra blocks zero num/den.
// ---------------------------------------------------------------------------
__global__ __launch_bounds__(256) void scan_partial(const int* __restrict__ cnt2,
                                                    int* __restrict__ bsum,
                                                    float* __restrict__ zeroreg) {
  const int t = threadIdx.x;
  if (blockIdx.x >= NBLK) {
    const int zb = blockIdx.x - NBLK;
    float4* dst = (float4*)zeroreg;
    const int total4 = 2 * NN * 64 / 4;
    const float4 z = make_float4(0.f, 0.f, 0.f, 0.f);
#pragma unroll 1
    for (int i = zb * 256 + t; i < total4; i += ZBLK * 256) dst[i] = z;
    return;
  }
  __shared__ int ws[4];
  const int base = blockIdx.x * 1024 + t * 4;
  int s = 0;
  if (base + 3 < NN) {
#pragma unroll
    for (int sh = 0; sh < 8; ++sh) {
      const int4 v = *(const int4*)(cnt2 + sh * NN + base);
      s += v.x + v.y + v.z + v.w;
    }
  } else {
#pragma unroll
    for (int i = 0; i < 4; ++i)
      if (base + i < NN)
#pragma unroll
        for (int sh = 0; sh < 8; ++sh) s += cnt2[sh * NN + base + i];
  }
#pragma unroll
  for (int off = 32; off; off >>= 1) s += __shfl_down(s, off, 64);
  if ((t & 63) == 0) ws[t >> 6] = s;
  __syncthreads();
  if (t == 0) bsum[blockIdx.x] = ws[0] + ws[1] + ws[2] + ws[3];
}

__global__ __launch_bounds__(256) void scan_final(const int* __restrict__ cnt2,
                                                  const int* __restrict__ bsum,
                                                  int* __restrict__ curs2) {
  __shared__ int tsum[256];
  __shared__ int sblk[64];
  const int t = threadIdx.x;
  if (t < 64) {
    const int mine = (t < NBLK) ? bsum[t] : 0;
    int v = mine;
#pragma unroll
    for (int off = 1; off < 64; off <<= 1) {
      const int u = __shfl_up(v, off, 64);
      if (t >= off) v += u;
    }
    sblk[t] = v - mine;
  }
  const int base = blockIdx.x * 1024 + t * 4;
  int c2[8][4];
  int v[4] = {0, 0, 0, 0};
  if (base + 3 < NN) {
#pragma unroll
    for (int sh = 0; sh < 8; ++sh) {
      const int4 x = *(const int4*)(cnt2 + sh * NN + base);
      c2[sh][0] = x.x; c2[sh][1] = x.y; c2[sh][2] = x.z; c2[sh][3] = x.w;
      v[0] += x.x; v[1] += x.y; v[2] += x.z; v[3] += x.w;
    }
  } else {
#pragma unroll
    for (int sh = 0; sh < 8; ++sh)
#pragma unroll
      for (int i = 0; i < 4; ++i) {
        const int c = (base + i < NN) ? cnt2[sh * NN + base + i] : 0;
        c2[sh][i] = c;
        v[i] += c;
      }
  }
  const int s = v[0] + v[1] + v[2] + v[3];
  tsum[t] = s;
  __syncthreads();
  for (int off = 1; off < 256; off <<= 1) {
    const int u = (t >= off) ? tsum[t - off] : 0;
    __syncthreads();
    tsum[t] += u;
    __syncthreads();
  }
  int ex = sblk[blockIdx.x] + tsum[t] - s;
  int offs[8][4];
#pragma unroll
  for (int i = 0; i < 4; ++i) {
    int run = ex;
#pragma unroll
    for (int sh = 0; sh < 8; ++sh) {
      offs[sh][i] = run;
      run += c2[sh][i];
    }
    ex += v[i];
  }
  if (base + 3 < NN) {
#pragma unroll
    for (int sh = 0; sh < 8; ++sh)
      *(int4*)(curs2 + sh * NN + base) =
          make_int4(offs[sh][0], offs[sh][1], offs[sh][2], offs[sh][3]);
  } else {
#pragma unroll
    for (int sh = 0; sh < 8; ++sh)
#pragma unroll
      for (int i = 0; i < 4; ++i)
        if (base + i < NN) curs2[sh * NN + base + i] = offs[sh][i];
  }
}

// scatter: block b owns edge chunk b (1024 edges); shard = b&7 (XCD-aligned).
__global__ __launch_bounds__(256) void scatter_kernel(const int* __restrict__ ei,
                                                      int* __restrict__ curs2,
                                                      int2* __restrict__ srt) {
  const int chunk = blockIdx.x;
  int* cs = curs2 + (chunk & 7) * NN;
  const int e0 = chunk * 1024 + threadIdx.x * 4;
  if (e0 >= ET) return;
  int s[4], d[4];
  if (e0 + 3 < EE) {
    const int4 sv = *(const int4*)(ei + e0);
    const int4 dv = *(const int4*)(ei + EE + e0);
    s[0] = sv.x; s[1] = sv.y; s[2] = sv.z; s[3] = sv.w;
    d[0] = dv.x; d[1] = dv.y; d[2] = dv.z; d[3] = dv.w;
  } else {
#pragma unroll
    for (int i = 0; i < 4; ++i) {
      const int e = e0 + i;
      if (e < EE) {
        s[i] = ei[e];
        d[i] = ei[EE + e];
      } else if (e < ET) {
        s[i] = d[i] = e - EE;
      } else {
        s[i] = d[i] = -1;
      }
    }
  }
#pragma unroll
  for (int i = 0; i < 4; ++i) {
    if (d[i] >= 0) {
      const int p = atomicAdd(&cs[d[i]], 1);
      srt[p] = make_int2(s[i], d[i]);
    }
  }
}

// ---------------------------------------------------------------------------
// Kernel A: fused sharded histogram + node projections (MFMA f16).
// ---------------------------------------------------------------------------
__global__ __launch_bounds__(256, 3) void node_proj(
    const float* __restrict__ x, const float* __restrict__ b_in,
    const _Float16* __restrict__ w16, const int* __restrict__ ei,
    int* __restrict__ cnt2, _Float16* __restrict__ vh,
    _Float16* __restrict__ kh, _Float16* __restrict__ qh) {
  __shared__ __align__(16) _Float16 wlds[4 * 4608];  // W_in|W_lin|W_src|W_dst
  __shared__ __align__(16) _Float16 hlds[4608];
  __shared__ float biasv[64];

  const int tid = threadIdx.x;
  const int nb = blockIdx.x * 64;
  const int l15 = tid & 15;
  const int quad = (tid >> 4) & 3;
  const int wband = tid >> 6;
  const int nloc = wband * 16 + l15;
  const int gn = nb + nloc;

  // sharded fire-and-forget histogram; chunk c = edges [c*1024,(c+1)*1024)
#pragma unroll 1
  for (int chunk = blockIdx.x; chunk < NCHUNK; chunk += gridDim.x) {
    int* cs = cnt2 + (chunk & 7) * NN;
    const int e0 = chunk * 1024 + tid * 4;
    if (e0 < ET) {
      int d[4];
      if (e0 + 3 < EE) {
        const int4 dv = *(const int4*)(ei + EE + e0);
        d[0] = dv.x; d[1] = dv.y; d[2] = dv.z; d[3] = dv.w;
      } else {
#pragma unroll
        for (int i = 0; i < 4; ++i) {
          const int e = e0 + i;
          d[i] = (e < EE) ? ei[EE + e] : ((e < ET) ? e - EE : -1);
        }
      }
#pragma unroll
      for (int i = 0; i < 4; ++i)
        if (d[i] >= 0) atomicAdd(&cs[d[i]], 1);
    }
  }

#pragma unroll
  for (int w = 0; w < 4; ++w) stage_w(wlds + w * 4608, w16 + w * 4096, tid);
  if (tid < 64) biasv[tid] = b_in[tid];

  // B-frag from x (f32 -> f16)
  f16x8 bfrag[2];
#pragma unroll
  for (int ks = 0; ks < 2; ++ks) {
    float y[8] = {0.f, 0.f, 0.f, 0.f, 0.f, 0.f, 0.f, 0.f};
    if (gn < NN) {
      const float4 a = *(const float4*)(x + (size_t)gn * 64 + ks * 32 + quad * 8);
      const float4 b = *(const float4*)(x + (size_t)gn * 64 + ks * 32 + quad * 8 + 4);
      y[0] = a.x; y[1] = a.y; y[2] = a.z; y[3] = a.w;
      y[4] = b.x; y[5] = b.y; y[6] = b.z; y[7] = b.w;
    }
    bfrag[ks] = pk8(y);
  }
  __syncthreads();  // B0

  // GEMM1: h = relu(W_in . x^T + b) -> hlds rows [n][o] f16
#pragma unroll
  for (int t = 0; t < 4; ++t) {
    f32x4 acc = {0.f, 0.f, 0.f, 0.f};
#pragma unroll
    for (int ks = 0; ks < 2; ++ks) {
      const f16x8 af = frag_ldh(wlds, t * 16 + l15, ks * 32 + quad * 8);
      acc = __builtin_amdgcn_mfma_f32_16x16x32_f16(af, bfrag[ks], acc, 0, 0, 0);
    }
    const int hb = t * 16 + quad * 4;
    *(f16x4*)(hlds + nloc * 72 + hb) =
        pk4(fmaxf(acc[0] + biasv[hb + 0], 0.f), fmaxf(acc[1] + biasv[hb + 1], 0.f),
            fmaxf(acc[2] + biasv[hb + 2], 0.f), fmaxf(acc[3] + biasv[hb + 3], 0.f));
  }
  __syncthreads();  // B1

  f16x8 hfrag[2];
#pragma unroll
  for (int ks = 0; ks < 2; ++ks)
    hfrag[ks] = frag_ldh(hlds, nloc, ks * 32 + quad * 8);

  _Float16* outs[3] = {vh, kh, qh};
#pragma unroll
  for (int p = 0; p < 3; ++p) {
    const _Float16* W = wlds + (p + 1) * 4608;
#pragma unroll
    for (int t = 0; t < 4; ++t) {
      f32x4 acc = {0.f, 0.f, 0.f, 0.f};
#pragma unroll
      for (int ks = 0; ks < 2; ++ks) {
        const f16x8 af = frag_ldh(W, t * 16 + l15, ks * 32 + quad * 8);
        acc = __builtin_amdgcn_mfma_f32_16x16x32_f16(af, hfrag[ks], acc, 0, 0, 0);
      }
      if (gn < NN) {
        *(f16x4*)(outs[p] + (size_t)gn * 64 + t * 16 + quad * 4) =
            pk4(acc[0], acc[1], acc[2], acc[3]);
      }
    }
  }
}

// ---------------------------------------------------------------------------
// Kernel B: MFMA (f16) edge pass (R2 structure + LDS diet + XCD swizzle).
//  - only W1 (then aliased) and h1 staged in LDS: smem = 16KB; W2/PW2 are
//    read directly from global as coalesced 16B A-fragments (64KB weight
//    table is L2-resident everywhere) -> LDS 18.4KB -> 8 blocks/CU target.
//  - pairb (msg,ex) 64x64 f16x2 = 16KB aliases W1|h1 after B1.
//  - bijective XCD swizzle: blocks with equal blockIdx%8 (same XCD under
//    round-robin dispatch) get a contiguous chunk of the dst-sorted edge
//    space -> qh gathers + num/den atomics become per-XCD L2-local.
// 3 barriers. launch_bounds(256,7): no forced spill (R3 lesson).
// ---------------------------------------------------------------------------
__global__ __launch_bounds__(256, 7) void edge_pass(
    const int2* __restrict__ srt, const float* __restrict__ pos,
    const _Float16* __restrict__ vh, const _Float16* __restrict__ kh,
    const _Float16* __restrict__ qh, const _Float16* __restrict__ w16,
    const float* __restrict__ att_b1, const float* __restrict__ att_b2,
    const float* __restrict__ pos_w1, const float* __restrict__ pos_b1,
    const float* __restrict__ pos_b2, float* __restrict__ num,
    float* __restrict__ den) {
  __shared__ __align__(16) _Float16 smem[8192];  // W1(4096h) | h1(4096h)
  __shared__ __align__(16) float posw1T[3 * 64];
  __shared__ float b1s[64], b2s[64], pb1s[64], pb2s[64];
  __shared__ int dsts[64];

  _Float16* W1 = smem;
  _Float16* HP = smem + 4096;     // h1 (64 x 64)
  f16x2* pairb = (f16x2*)smem;    // 64ch x 64slot = 16KB, aliases W1|h1

  const int tid = threadIdx.x;
  const int l15 = tid & 15;
  const int quad = (tid >> 4) & 3;
  const int wband = tid >> 6;
  const int eloc = wband * 16 + l15;

  // bijective XCD swizzle (m204 form): nwg = 13282 = 8*1660 + 2
  const int nwg = (ET + 63) / 64;
  const int q8 = nwg >> 3, rm = nwg & 7;
  const int xcd = blockIdx.x & 7, idx = blockIdx.x >> 3;
  const int wg =
      (xcd < rm ? xcd * (q8 + 1) : rm * (q8 + 1) + (xcd - rm) * q8) + idx;
  const int eb = wg * 64;

  // ---- phase 0a: per-lane edge read + B-frag: ad = q[dst]-k[src] (f16)
  int s_mine, d_mine;
  f16x8 bfrag[2];
  float dp0, dp1, dp2;
  {
    const int e = eb + eloc;
    int2 sd = make_int2(0, 0);
    int valid_d = -1;
    if (e < ET) {
      sd = srt[e];
      valid_d = sd.y;
    }
    s_mine = sd.x;
    d_mine = sd.y;
    if (quad == 0) dsts[eloc] = valid_d;
#pragma unroll
    for (int ks = 0; ks < 2; ++ks) {
      const f16x8 qv =
          *(const f16x8*)(qh + (size_t)d_mine * 64 + ks * 32 + quad * 8);
      const f16x8 kv =
          *(const f16x8*)(kh + (size_t)s_mine * 64 + ks * 32 + quad * 8);
      bfrag[ks] = qv - kv;
    }
    dp0 = pos[(size_t)d_mine * 3 + 0] - pos[(size_t)s_mine * 3 + 0];
    dp1 = pos[(size_t)d_mine * 3 + 1] - pos[(size_t)s_mine * 3 + 1];
    dp2 = pos[(size_t)d_mine * 3 + 2] - pos[(size_t)s_mine * 3 + 2];
  }

  // ---- phase 0b: stage W1 (f16), biases, posw1T
  stage_ws(W1, w16 + 4 * 4096, tid);
  if (tid < 64) {
    b1s[tid] = att_b1[tid];
    b2s[tid] = att_b2[tid] * 1.44269504088896340736f;  // W2 prescaled in prep
    pb1s[tid] = pos_b1[tid];
    pb2s[tid] = pos_b2[tid];
    posw1T[0 * 64 + tid] = pos_w1[tid * 3 + 0];
    posw1T[1 * 64 + tid] = pos_w1[tid * 3 + 1];
    posw1T[2 * 64 + tid] = pos_w1[tid * 3 + 2];
  }
  __syncthreads();  // B0

  // ---- GEMM1: h1 = relu(W1 . ad^T + b1) -> HP rows [e][h] f16 (wave-private)
#pragma unroll
  for (int t = 0; t < 4; ++t) {
    f32x4 acc = {0.f, 0.f, 0.f, 0.f};
#pragma unroll
    for (int ks = 0; ks < 2; ++ks) {
      const f16x8 af = frag_lds(W1, t * 16 + l15, ks * 32 + quad * 8);
      acc = __builtin_amdgcn_mfma_f32_16x16x32_f16(af, bfrag[ks], acc, 0, 0, 0);
    }
    const int hb = t * 16 + quad * 4;
    *(f16x4*)((char*)HP + swzb(eloc, hb * 2)) =
        pk4(fmaxf(acc[0] + b1s[hb + 0], 0.f), fmaxf(acc[1] + b1s[hb + 1], 0.f),
            fmaxf(acc[2] + b1s[hb + 2], 0.f), fmaxf(acc[3] + b1s[hb + 3], 0.f));
  }

  // ---- hp in registers (k=3 pos-MLP layer 1 for this lane's 16 k-values)
  f16x8 hpfrag[2];
#pragma unroll
  for (int ks = 0; ks < 2; ++ks) {
    float hv[8];
#pragma unroll
    for (int j = 0; j < 8; ++j) {
      const int i = ks * 32 + quad * 8 + j;
      float h = pb1s[i];
      h = fmaf(dp0, posw1T[i], h);
      h = fmaf(dp1, posw1T[64 + i], h);
      h = fmaf(dp2, posw1T[128 + i], h);
      hv[j] = fmaxf(h, 0.f);
    }
    hpfrag[ks] = pk8(hv);
  }

  // ---- GEMM2: alpha' = relu(W2' . h1^T + b2'); ex = exp2(alpha')
  // W2 rows read DIRECTLY from global (L2-hot 8KB table, coalesced 16B/lane).
  // h1 rows of own band: same-wave producer/consumer -> lgkmcnt only.
  float ex[16];
  {
    const _Float16* w2g = w16 + 5 * 4096;
    f16x8 hfrag[2];
#pragma unroll
    for (int ks = 0; ks < 2; ++ks)
      hfrag[ks] = frag_lds(HP, eloc, ks * 32 + quad * 8);
#pragma unroll
    for (int t = 0; t < 4; ++t) {
      f32x4 acc = {0.f, 0.f, 0.f, 0.f};
#pragma unroll
      for (int ks = 0; ks < 2; ++ks) {
        const f16x8 af =
            *(const f16x8*)(w2g + (t * 16 + l15) * 64 + ks * 32 + quad * 8);
        acc = __builtin_amdgcn_mfma_f32_16x16x32_f16(af, hfrag[ks], acc, 0, 0, 0);
      }
      const int ob = t * 16 + quad * 4;
#pragma unroll
      for (int r = 0; r < 4; ++r)
        ex[t * 4 + r] = __builtin_exp2f(fmaxf(acc[r] + b2s[ob + r], 0.f));
    }
  }
  // v gather issued now (global; overlaps barrier + GEMM3 weight loads)
  float vr[16];
#pragma unroll
  for (int t = 0; t < 4; ++t) {
    const f16x4 v4 = *(const f16x4*)(vh + (size_t)s_mine * 64 + t * 16 + quad * 4);
    vr[t * 4 + 0] = (float)v4[0];
    vr[t * 4 + 1] = (float)v4[1];
    vr[t * 4 + 2] = (float)v4[2];
    vr[t * 4 + 3] = (float)v4[3];
  }
  __syncthreads();  // B1: all waves done with W1 (GEMM1) and h1 (GEMM2)

  // ---- GEMM3: delta = relu(PW2 . hp^T + pb2), PW2 rows direct from global
  float del[16];
  {
    const _Float16* pw2g = w16 + 6 * 4096;
#pragma unroll
    for (int t = 0; t < 4; ++t) {
      f32x4 acc = {0.f, 0.f, 0.f, 0.f};
#pragma unroll
      for (int ks = 0; ks < 2; ++ks) {
        const f16x8 af =
            *(const f16x8*)(pw2g + (t * 16 + l15) * 64 + ks * 32 + quad * 8);
        acc = __builtin_amdgcn_mfma_f32_16x16x32_f16(af, hpfrag[ks], acc, 0, 0, 0);
      }
      const int ob = t * 16 + quad * 4;
#pragma unroll
      for (int r = 0; r < 4; ++r)
        del[t * 4 + r] = fmaxf(acc[r] + pb2s[ob + r], 0.f);
    }
  }

  // ---- phase 5: (msg, ex) -> pairb f16x2 (W1|h1 region dead since B1)
#pragma unroll
  for (int t = 0; t < 4; ++t) {
#pragma unroll
    for (int r = 0; r < 4; ++r) {
      const int o = t * 16 + quad * 4 + r;
      const float e_ = ex[t * 4 + r];
      pairb[o * 64 + psl(eloc, o)] =
          pk2(e_ * (vr[t * 4 + r] + del[t * 4 + r]), e_);
    }
  }
  __syncthreads();  // B2

  // ---- phase 6: segmented reduce over sorted-dst runs, then atomics
  {
    const int c = tid & 63;
    const int r = tid >> 6;
    float am = 0.f, ae = 0.f;
    int cur = -1;
#pragma unroll 1
    for (int t2 = 0; t2 < 16; ++t2) {
      const int el = r * 16 + t2;
      const int d = dsts[el];
      if (d != cur) {
        if (cur >= 0) {
          unsafeAtomicAdd(num + (size_t)cur * 64 + c, am);
          unsafeAtomicAdd(den + (size_t)cur * 64 + c, ae);
        }
        cur = d;
        am = 0.f;
        ae = 0.f;
      }
      if (d >= 0) {
        const f16x2 pe = pairb[c * 64 + psl(el, c)];
        am += (float)pe[0];
        ae += (float)pe[1];
      }
    }
    if (cur >= 0) {
      unsafeAtomicAdd(num + (size_t)cur * 64 + c, am);
      unsafeAtomicAdd(den + (size_t)cur * 64 + c, ae);
    }
  }
}

// ---------------------------------------------------------------------------
// Kernel C: out = relu((num/(den+1e-16)) @ W_out.T + b_out), MFMA f16.
// ---------------------------------------------------------------------------
__global__ __launch_bounds__(256, 4) void out_proj(
    const float* __restrict__ num, const float* __restrict__ den,
    const _Float16* __restrict__ w16, const float* __restrict__ b_out,
    float* __restrict__ out) {
  __shared__ __align__(16) _Float16 wlds[4608];
  __shared__ float biasv[64];

  const int tid = threadIdx.x;
  const int nb = blockIdx.x * 64;
  const int l15 = tid & 15;
  const int quad = (tid >> 4) & 3;
  const int wband = tid >> 6;
  const int gn = nb + wband * 16 + l15;

  stage_w(wlds, w16 + 7 * 4096, tid);
  if (tid < 64) biasv[tid] = b_out[tid];

  f16x8 bfrag[2];
#pragma unroll
  for (int ks = 0; ks < 2; ++ks) {
    float y[8] = {0.f, 0.f, 0.f, 0.f, 0.f, 0.f, 0.f, 0.f};
    if (gn < NN) {
      const size_t base = (size_t)gn * 64 + ks * 32 + quad * 8;
      const float4 n0 = *(const float4*)(num + base);
      const float4 n1 = *(const float4*)(num + base + 4);
      const float4 d0 = *(const float4*)(den + base);
      const float4 d1 = *(const float4*)(den + base + 4);
      y[0] = n0.x / (d0.x + 1e-16f); y[1] = n0.y / (d0.y + 1e-16f);
      y[2] = n0.z / (d0.z + 1e-16f); y[3] = n0.w / (d0.w + 1e-16f);
      y[4] = n1.x / (d1.x + 1e-16f); y[5] = n1.y / (d1.y + 1e-16f);
      y[6] = n1.z / (d1.z + 1e-16f); y[7] = n1.w / (d1.w + 1e-16f);
    }
    bfrag[ks] = pk8(y);
  }
  __syncthreads();

#pragma unroll
  for (int t = 0; t < 4; ++t) {
    f32x4 acc = {0.f, 0.f, 0.f, 0.f};
#pragma unroll
    for (int ks = 0; ks < 2; ++ks) {
      const f16x8 af = frag_ldh(wlds, t * 16 + l15, ks * 32 + quad * 8);
      acc = __builtin_amdgcn_mfma_f32_16x16x32_f16(af, bfrag[ks], acc, 0, 0, 0);
    }
    if (gn < NN) {
      const int ob = t * 16 + quad * 4;
      float4 r;
      r.x = fmaxf(acc[0] + biasv[ob + 0], 0.f);
      r.y = fmaxf(acc[1] + biasv[ob + 1], 0.f);
      r.z = fmaxf(acc[2] + biasv[ob + 2], 0.f);
      r.w = fmaxf(acc[3] + biasv[ob + 3], 0.f);
      *(float4*)(out + (size_t)gn * 64 + ob) = r;
    }
  }
}

extern "C" void kernel_launch(void* const* d_in, const int* in_sizes, int n_in,
                              void* d_out, int out_size, void* d_ws,
                              size_t ws_size, hipStream_t stream) {
  const float* x      = (const float*)d_in[0];
  const float* pos    = (const float*)d_in[1];
  const int*   ei     = (const int*)d_in[2];
  const float* W_in   = (const float*)d_in[3];
  const float* b_in   = (const float*)d_in[4];
  const float* W_out  = (const float*)d_in[5];
  const float* b_out  = (const float*)d_in[6];
  const float* W_lin  = (const float*)d_in[7];
  const float* W_src  = (const float*)d_in[8];
  const float* W_dst  = (const float*)d_in[9];
  const float* pos_w1 = (const float*)d_in[10];
  const float* pos_b1 = (const float*)d_in[11];
  const float* pos_w2 = (const float*)d_in[12];
  const float* pos_b2 = (const float*)d_in[13];
  const float* att_w1 = (const float*)d_in[14];
  const float* att_b1 = (const float*)d_in[15];
  const float* att_w2 = (const float*)d_in[16];
  const float* att_b2 = (const float*)d_in[17];

  float* ws = (float*)d_ws;
  const size_t NC = (size_t)NN * C;
  float* num = ws;                       // NC f32
  float* den = ws + NC;                  // NC f32
  _Float16* vh = (_Float16*)(ws + 2 * NC);  // NC f16
  _Float16* kh = vh + NC;                    // NC f16
  _Float16* qh = kh + NC;                    // NC f16
  _Float16* w16 = qh + NC;                   // 8*4096 f16
  int* ib     = (int*)(w16 + 8 * 4096);
  int* cnt2   = ib;                      // 8*NN
  int* curs2  = ib + 8 * NN;             // 8*NN
  int* bsum   = ib + 16 * NN;            // NBLK
  int2* srt   = (int2*)(((uintptr_t)(bsum + NBLK) + 15) & ~(uintptr_t)15);

  const dim3 blk(256);
  prep_kernel<<<dim3(64), blk, 0, stream>>>(W_in, W_lin, W_src, W_dst, att_w1,
                                            att_w2, pos_w2, W_out, w16, cnt2);
  node_proj<<<dim3((NN + 63) / 64), blk, 0, stream>>>(x, b_in, w16, ei, cnt2,
                                                      vh, kh, qh);
  scan_partial<<<dim3(NBLK + ZBLK), blk, 0, stream>>>(cnt2, bsum, num);
  scan_final<<<dim3(NBLK), blk, 0, stream>>>(cnt2, bsum, curs2);
  scatter_kernel<<<dim3(NCHUNK), blk, 0, stream>>>(ei, curs2, srt);
  edge_pass<<<dim3((ET + 63) / 64), blk, 0, stream>>>(
      srt, pos, vh, kh, qh, w16, att_b1, att_b2, pos_w1, pos_b1, pos_b2, num,
      den);
  out_proj<<<dim3((NN + 63) / 64), blk, 0, stream>>>(num, den, w16, b_out,
                                                     (float*)d_out);
}

// Round 6
// 309.766 us; speedup vs baseline: 1.5366x; 1.2052x over previous
//
#include <hip/hip_runtime.h>
#include <math.h>

#define NN 50000
#define EE 800000
#define ET (EE + NN)   // 850000 edges incl. self-loops
#define C  64
#define NBLK 49        // ceil(NN/1024) scan blocks
#define NCHUNK 831     // ceil(ET/1024) edge chunks
#define ZBLK 463       // zeroing blocks appended to scan_partial

typedef __attribute__((ext_vector_type(8))) _Float16 f16x8;
typedef __attribute__((ext_vector_type(4))) _Float16 f16x4;
typedef __attribute__((ext_vector_type(2))) _Float16 f16x2;
typedef __attribute__((ext_vector_type(4))) float f32x4;

__device__ __forceinline__ f16x2 pk2(float a, float b) {
  return __builtin_bit_cast(f16x2, __builtin_amdgcn_cvt_pkrtz(a, b));
}
__device__ __forceinline__ f16x4 pk4(float a, float b, float c, float d) {
  return __builtin_shufflevector(pk2(a, b), pk2(c, d), 0, 1, 2, 3);
}
__device__ __forceinline__ f16x8 pk8(const float* y) {
  const f16x4 lo = pk4(y[0], y[1], y[2], y[3]);
  const f16x4 hi = pk4(y[4], y[5], y[6], y[7]);
  return __builtin_shufflevector(lo, hi, 0, 1, 2, 3, 4, 5, 6, 7);
}

// ---------------- padded (stride-72) LDS helpers: out_proj ------------------
__device__ __forceinline__ f16x8 frag_ldh(const _Float16* base, int row,
                                          int kofs) {
  return *(const f16x8*)(base + row * 72 + kofs);
}
__device__ __forceinline__ void stage_w(_Float16* __restrict__ dst,
                                        const _Float16* __restrict__ src16,
                                        int tid) {
  const f16x8* src = (const f16x8*)(src16 + tid * 16);
  _Float16* d = dst + (tid >> 2) * 72 + (tid & 3) * 16;
  ((f16x8*)d)[0] = src[0];
  ((f16x8*)d)[1] = src[1];
}

// ---------------- dense (stride-64) XOR-swizzled LDS helpers ----------------
// phys byte = row*128 + (colbyte ^ ((row&7)<<4)); bijective per 16B block,
// preserves 16B/8B alignment; 2-way max bank aliasing (free on CDNA4).
__device__ __forceinline__ int swzb(int row, int colbyte) {
  return row * 128 + (colbyte ^ ((row & 7) << 4));
}
__device__ __forceinline__ f16x8 frag_lds(const _Float16* base, int row,
                                          int kofs) {
  return *(const f16x8*)((const char*)base + swzb(row, kofs * 2));
}
__device__ __forceinline__ void stage_ws(_Float16* __restrict__ dst,
                                         const _Float16* __restrict__ src16,
                                         int tid) {
  const f16x8* src = (const f16x8*)(src16 + tid * 16);
  const int row = tid >> 2;
  const int c0 = (tid & 3) * 32;  // bytes
  *(f16x8*)((char*)dst + swzb(row, c0)) = src[0];
  *(f16x8*)((char*)dst + swzb(row, c0 + 16)) = src[1];
}

// pairb swizzle: 2-way banks on BOTH write (vary e,o-quad) and read (vary o)
__device__ __forceinline__ int psl(int e, int o) {
  return (e + 2 * o + (o >> 5)) & 63;
}

// ---------------------------------------------------------------------------
// prep: convert 8 weight matrices f32 -> f16 (blocks 0..7) + zero cnt shards
// order: W_in, W_lin, W_src, W_dst, att_w1, att_w2, pos_w2, W_out
// att_w2 is pre-scaled by log2(e) so edge_pass can use exp2 directly.
// ---------------------------------------------------------------------------
__global__ __launch_bounds__(256) void prep_kernel(
    const float* __restrict__ W_in, const float* __restrict__ W_lin,
    const float* __restrict__ W_src, const float* __restrict__ W_dst,
    const float* __restrict__ att_w1, const float* __restrict__ att_w2,
    const float* __restrict__ pos_w2, const float* __restrict__ W_out,
    _Float16* __restrict__ w16, int* __restrict__ cnt2) {
  if (blockIdx.x < 8) {
    const float* Ws[8] = {W_in, W_lin, W_src, W_dst, att_w1, att_w2, pos_w2,
                          W_out};
    const float* src = Ws[blockIdx.x];
    _Float16* dst = w16 + blockIdx.x * 4096;
    const float sc = (blockIdx.x == 5) ? 1.44269504088896340736f : 1.0f;
#pragma unroll
    for (int i = threadIdx.x * 4; i < 4096; i += 1024) {
      const float4 w = *(const float4*)(src + i);
      *(f16x4*)(dst + i) = pk4(w.x * sc, w.y * sc, w.z * sc, w.w * sc);
    }
  }
  // zero all 8 counter shards (8*NN ints = 2*NN int4) across 64 blocks
  int4* cz = (int4*)cnt2;
#pragma unroll 1
  for (int i = blockIdx.x * 256 + threadIdx.x; i < 2 * NN; i += 64 * 256)
    cz[i] = make_int4(0, 0, 0, 0);
}

// ---------------------------------------------------------------------------
// Scan over sharded counters; extra blocks zero num/den.
// ---------------------------------------------------------------------------
__global__ __launch_bounds__(256) void scan_partial(const int* __restrict__ cnt2,
                                                    int* __restrict__ bsum,
                                                    float* __restrict__ zeroreg) {
  const int t = threadIdx.x;
  if (blockIdx.x >= NBLK) {
    const int zb = blockIdx.x - NBLK;
    float4* dst = (float4*)zeroreg;
    const int total4 = 2 * NN * 64 / 4;
    const float4 z = make_float4(0.f, 0.f, 0.f, 0.f);
#pragma unroll 1
    for (int i = zb * 256 + t; i < total4; i += ZBLK * 256) dst[i] = z;
    return;
  }
  __shared__ int ws[4];
  const int base = blockIdx.x * 1024 + t * 4;
  int s = 0;
  if (base + 3 < NN) {
#pragma unroll
    for (int sh = 0; sh < 8; ++sh) {
      const int4 v = *(const int4*)(cnt2 + sh * NN + base);
      s += v.x + v.y + v.z + v.w;
    }
  } else {
#pragma unroll
    for (int i = 0; i < 4; ++i)
      if (base + i < NN)
#pragma unroll
        for (int sh = 0; sh < 8; ++sh) s += cnt2[sh * NN + base + i];
  }
#pragma unroll
  for (int off = 32; off; off >>= 1) s += __shfl_down(s, off, 64);
  if ((t & 63) == 0) ws[t >> 6] = s;
  __syncthreads();
  if (t == 0) bsum[blockIdx.x] = ws[0] + ws[1] + ws[2] + ws[3];
}

__global__ __launch_bounds__(256) void scan_final(const int* __restrict__ cnt2,
                                                  const int* __restrict__ bsum,
                                                  int* __restrict__ curs2) {
  __shared__ int tsum[256];
  __shared__ int sblk[64];
  const int t = threadIdx.x;
  if (t < 64) {
    const int mine = (t < NBLK) ? bsum[t] : 0;
    int v = mine;
#pragma unroll
    for (int off = 1; off < 64; off <<= 1) {
      const int u = __shfl_up(v, off, 64);
      if (t >= off) v += u;
    }
    sblk[t] = v - mine;
  }
  const int base = blockIdx.x * 1024 + t * 4;
  int c2[8][4];
  int v[4] = {0, 0, 0, 0};
  if (base + 3 < NN) {
#pragma unroll
    for (int sh = 0; sh < 8; ++sh) {
      const int4 x = *(const int4*)(cnt2 + sh * NN + base);
      c2[sh][0] = x.x; c2[sh][1] = x.y; c2[sh][2] = x.z; c2[sh][3] = x.w;
      v[0] += x.x; v[1] += x.y; v[2] += x.z; v[3] += x.w;
    }
  } else {
#pragma unroll
    for (int sh = 0; sh < 8; ++sh)
#pragma unroll
      for (int i = 0; i < 4; ++i) {
        const int c = (base + i < NN) ? cnt2[sh * NN + base + i] : 0;
        c2[sh][i] = c;
        v[i] += c;
      }
  }
  const int s = v[0] + v[1] + v[2] + v[3];
  tsum[t] = s;
  __syncthreads();
  for (int off = 1; off < 256; off <<= 1) {
    const int u = (t >= off) ? tsum[t - off] : 0;
    __syncthreads();
    tsum[t] += u;
    __syncthreads();
  }
  int ex = sblk[blockIdx.x] + tsum[t] - s;
  int offs[8][4];
#pragma unroll
  for (int i = 0; i < 4; ++i) {
    int run = ex;
#pragma unroll
    for (int sh = 0; sh < 8; ++sh) {
      offs[sh][i] = run;
      run += c2[sh][i];
    }
    ex += v[i];
  }
  if (base + 3 < NN) {
#pragma unroll
    for (int sh = 0; sh < 8; ++sh)
      *(int4*)(curs2 + sh * NN + base) =
          make_int4(offs[sh][0], offs[sh][1], offs[sh][2], offs[sh][3]);
  } else {
#pragma unroll
    for (int sh = 0; sh < 8; ++sh)
#pragma unroll
      for (int i = 0; i < 4; ++i)
        if (base + i < NN) curs2[sh * NN + base + i] = offs[sh][i];
  }
}

// scatter: block b owns edge chunk b (1024 edges); shard = b&7 (XCD-aligned).
__global__ __launch_bounds__(256) void scatter_kernel(const int* __restrict__ ei,
                                                      int* __restrict__ curs2,
                                                      int2* __restrict__ srt) {
  const int chunk = blockIdx.x;
  int* cs = curs2 + (chunk & 7) * NN;
  const int e0 = chunk * 1024 + threadIdx.x * 4;
  if (e0 >= ET) return;
  int s[4], d[4];
  if (e0 + 3 < EE) {
    const int4 sv = *(const int4*)(ei + e0);
    const int4 dv = *(const int4*)(ei + EE + e0);
    s[0] = sv.x; s[1] = sv.y; s[2] = sv.z; s[3] = sv.w;
    d[0] = dv.x; d[1] = dv.y; d[2] = dv.z; d[3] = dv.w;
  } else {
#pragma unroll
    for (int i = 0; i < 4; ++i) {
      const int e = e0 + i;
      if (e < EE) {
        s[i] = ei[e];
        d[i] = ei[EE + e];
      } else if (e < ET) {
        s[i] = d[i] = e - EE;
      } else {
        s[i] = d[i] = -1;
      }
    }
  }
#pragma unroll
  for (int i = 0; i < 4; ++i) {
    if (d[i] >= 0) {
      const int p = atomicAdd(&cs[d[i]], 1);
      srt[p] = make_int2(s[i], d[i]);
    }
  }
}

// ---------------------------------------------------------------------------
// Kernel A: fused sharded histogram + node projections (MFMA f16).
// Dense swizzled LDS: 4*8KB weights + 8KB h = 40.0KB exactly -> 4 blocks/CU
// (was 46KB padded -> 3). b_in read per-thread from global (L2-hot).
// ---------------------------------------------------------------------------
__global__ __launch_bounds__(256, 4) void node_proj(
    const float* __restrict__ x, const float* __restrict__ b_in,
    const _Float16* __restrict__ w16, const int* __restrict__ ei,
    int* __restrict__ cnt2, _Float16* __restrict__ vh,
    _Float16* __restrict__ kh, _Float16* __restrict__ qh) {
  __shared__ __align__(16) _Float16 wlds[4 * 4096];  // W_in|W_lin|W_src|W_dst
  __shared__ __align__(16) _Float16 hlds[4096];

  const int tid = threadIdx.x;
  const int nb = blockIdx.x * 64;
  const int l15 = tid & 15;
  const int quad = (tid >> 4) & 3;
  const int wband = tid >> 6;
  const int nloc = wband * 16 + l15;
  const int gn = nb + nloc;

  // sharded fire-and-forget histogram; chunk c = edges [c*1024,(c+1)*1024)
#pragma unroll 1
  for (int chunk = blockIdx.x; chunk < NCHUNK; chunk += gridDim.x) {
    int* cs = cnt2 + (chunk & 7) * NN;
    const int e0 = chunk * 1024 + tid * 4;
    if (e0 < ET) {
      int d[4];
      if (e0 + 3 < EE) {
        const int4 dv = *(const int4*)(ei + EE + e0);
        d[0] = dv.x; d[1] = dv.y; d[2] = dv.z; d[3] = dv.w;
      } else {
#pragma unroll
        for (int i = 0; i < 4; ++i) {
          const int e = e0 + i;
          d[i] = (e < EE) ? ei[EE + e] : ((e < ET) ? e - EE : -1);
        }
      }
#pragma unroll
      for (int i = 0; i < 4; ++i)
        if (d[i] >= 0) atomicAdd(&cs[d[i]], 1);
    }
  }

#pragma unroll
  for (int w = 0; w < 4; ++w) stage_ws(wlds + w * 4096, w16 + w * 4096, tid);

  // B-frag from x (f32 -> f16)
  f16x8 bfrag[2];
#pragma unroll
  for (int ks = 0; ks < 2; ++ks) {
    float y[8] = {0.f, 0.f, 0.f, 0.f, 0.f, 0.f, 0.f, 0.f};
    if (gn < NN) {
      const float4 a = *(const float4*)(x + (size_t)gn * 64 + ks * 32 + quad * 8);
      const float4 b = *(const float4*)(x + (size_t)gn * 64 + ks * 32 + quad * 8 + 4);
      y[0] = a.x; y[1] = a.y; y[2] = a.z; y[3] = a.w;
      y[4] = b.x; y[5] = b.y; y[6] = b.z; y[7] = b.w;
    }
    bfrag[ks] = pk8(y);
  }
  __syncthreads();  // B0

  // GEMM1: h = relu(W_in . x^T + b) -> hlds rows [n][o] f16
  __builtin_amdgcn_s_setprio(1);
#pragma unroll
  for (int t = 0; t < 4; ++t) {
    f32x4 acc = {0.f, 0.f, 0.f, 0.f};
#pragma unroll
    for (int ks = 0; ks < 2; ++ks) {
      const f16x8 af = frag_lds(wlds, t * 16 + l15, ks * 32 + quad * 8);
      acc = __builtin_amdgcn_mfma_f32_16x16x32_f16(af, bfrag[ks], acc, 0, 0, 0);
    }
    const int hb = t * 16 + quad * 4;
    const float4 bv = *(const float4*)(b_in + hb);
    *(f16x4*)((char*)hlds + swzb(nloc, hb * 2)) =
        pk4(fmaxf(acc[0] + bv.x, 0.f), fmaxf(acc[1] + bv.y, 0.f),
            fmaxf(acc[2] + bv.z, 0.f), fmaxf(acc[3] + bv.w, 0.f));
  }
  __builtin_amdgcn_s_setprio(0);
  __syncthreads();  // B1

  f16x8 hfrag[2];
#pragma unroll
  for (int ks = 0; ks < 2; ++ks)
    hfrag[ks] = frag_lds(hlds, nloc, ks * 32 + quad * 8);

  _Float16* outs[3] = {vh, kh, qh};
#pragma unroll
  for (int p = 0; p < 3; ++p) {
    const _Float16* W = wlds + (p + 1) * 4096;
#pragma unroll
    for (int t = 0; t < 4; ++t) {
      f32x4 acc = {0.f, 0.f, 0.f, 0.f};
#pragma unroll
      for (int ks = 0; ks < 2; ++ks) {
        const f16x8 af = frag_lds(W, t * 16 + l15, ks * 32 + quad * 8);
        acc = __builtin_amdgcn_mfma_f32_16x16x32_f16(af, hfrag[ks], acc, 0, 0, 0);
      }
      if (gn < NN) {
        *(f16x4*)(outs[p] + (size_t)gn * 64 + t * 16 + quad * 4) =
            pk4(acc[0], acc[1], acc[2], acc[3]);
      }
    }
  }
}

// ---------------------------------------------------------------------------
// Kernel B: MFMA (f16) edge pass (exact R2 structure + instruction diet):
//  - fdot2 accumulate in phase 6 (lossless, -2 insts/channel)
//  - dp computed once per edge by quad0, shared via 384B LDS (f16)
//  - setprio(1) around MFMA clusters (T5: 6 blocks x 4 waves, phase-diverse)
// LDS 27.0KB -> still 6 blocks/CU. 4 barriers.
// ---------------------------------------------------------------------------
__global__ __launch_bounds__(256, 6) void edge_pass(
    const int2* __restrict__ srt, const float* __restrict__ pos,
    const _Float16* __restrict__ vh, const _Float16* __restrict__ kh,
    const _Float16* __restrict__ qh, const _Float16* __restrict__ w16,
    const float* __restrict__ att_b1, const float* __restrict__ att_b2,
    const float* __restrict__ pos_w1, const float* __restrict__ pos_b1,
    const float* __restrict__ pos_b2, float* __restrict__ num,
    float* __restrict__ den) {
  __shared__ __align__(16) _Float16 smem[12288];  // W1|W2|HP dense
  __shared__ __align__(16) float posw1T[3 * 64];
  __shared__ float b1s[64], b2s[64], pb1s[64], pb2s[64];
  __shared__ int dsts[64];
  __shared__ _Float16 dph[3 * 64];  // per-edge dp (f16), written by quad0

  _Float16* W1 = smem;
  _Float16* W2 = smem + 4096;
  _Float16* HP = smem + 8192;     // h1, then PW2
  f16x2* pairb = (f16x2*)smem;    // 64ch x 64slot = 16KB, aliases W1+W2 exactly

  const int tid = threadIdx.x;
  const int eb = blockIdx.x * 64;
  const int l15 = tid & 15;
  const int quad = (tid >> 4) & 3;
  const int wband = tid >> 6;
  const int eloc = wband * 16 + l15;

  // ---- phase 0a: per-lane edge read + B-frag: ad = q[dst]-k[src] (f16)
  int s_mine, d_mine;
  f16x8 bfrag[2];
  {
    const int e = eb + eloc;
    int2 sd = make_int2(0, 0);
    int valid_d = -1;
    if (e < ET) {
      sd = srt[e];
      valid_d = sd.y;
    }
    s_mine = sd.x;
    d_mine = sd.y;
    if (quad == 0) {
      dsts[eloc] = valid_d;
      // dp computed ONCE per edge (quads 1-3 previously redundant)
      const float d0 = pos[(size_t)d_mine * 3 + 0] - pos[(size_t)s_mine * 3 + 0];
      const float d1 = pos[(size_t)d_mine * 3 + 1] - pos[(size_t)s_mine * 3 + 1];
      const float d2 = pos[(size_t)d_mine * 3 + 2] - pos[(size_t)s_mine * 3 + 2];
      dph[0 * 64 + eloc] = (_Float16)d0;
      dph[1 * 64 + eloc] = (_Float16)d1;
      dph[2 * 64 + eloc] = (_Float16)d2;
    }
#pragma unroll
    for (int ks = 0; ks < 2; ++ks) {
      const f16x8 qv =
          *(const f16x8*)(qh + (size_t)d_mine * 64 + ks * 32 + quad * 8);
      const f16x8 kv =
          *(const f16x8*)(kh + (size_t)s_mine * 64 + ks * 32 + quad * 8);
      bfrag[ks] = qv - kv;
    }
  }

  // ---- phase 0b: stage W1, W2 (f16), biases, posw1T
  stage_ws(W1, w16 + 4 * 4096, tid);
  stage_ws(W2, w16 + 5 * 4096, tid);
  if (tid < 64) {
    b1s[tid] = att_b1[tid];
    b2s[tid] = att_b2[tid] * 1.44269504088896340736f;  // W2 prescaled in prep
    pb1s[tid] = pos_b1[tid];
    pb2s[tid] = pos_b2[tid];
    posw1T[0 * 64 + tid] = pos_w1[tid * 3 + 0];
    posw1T[1 * 64 + tid] = pos_w1[tid * 3 + 1];
    posw1T[2 * 64 + tid] = pos_w1[tid * 3 + 2];
  }
  __syncthreads();  // B0 (also publishes dph)

  // ---- GEMM1: h1 = relu(W1 . ad^T + b1) -> HP rows [e][h] f16 (wave-private)
  __builtin_amdgcn_s_setprio(1);
#pragma unroll
  for (int t = 0; t < 4; ++t) {
    f32x4 acc = {0.f, 0.f, 0.f, 0.f};
#pragma unroll
    for (int ks = 0; ks < 2; ++ks) {
      const f16x8 af = frag_lds(W1, t * 16 + l15, ks * 32 + quad * 8);
      acc = __builtin_amdgcn_mfma_f32_16x16x32_f16(af, bfrag[ks], acc, 0, 0, 0);
    }
    const int hb = t * 16 + quad * 4;
    *(f16x4*)((char*)HP + swzb(eloc, hb * 2)) =
        pk4(fmaxf(acc[0] + b1s[hb + 0], 0.f), fmaxf(acc[1] + b1s[hb + 1], 0.f),
            fmaxf(acc[2] + b1s[hb + 2], 0.f), fmaxf(acc[3] + b1s[hb + 3], 0.f));
  }
  __builtin_amdgcn_s_setprio(0);

  // ---- hp in registers (k=3 pos-MLP layer 1 for this lane's 16 k-values)
  const float dp0 = (float)dph[0 * 64 + eloc];
  const float dp1 = (float)dph[1 * 64 + eloc];
  const float dp2 = (float)dph[2 * 64 + eloc];
  f16x8 hpfrag[2];
#pragma unroll
  for (int ks = 0; ks < 2; ++ks) {
    float hv[8];
#pragma unroll
    for (int j = 0; j < 8; ++j) {
      const int i = ks * 32 + quad * 8 + j;
      float h = pb1s[i];
      h = fmaf(dp0, posw1T[i], h);
      h = fmaf(dp1, posw1T[64 + i], h);
      h = fmaf(dp2, posw1T[128 + i], h);
      hv[j] = fmaxf(h, 0.f);
    }
    hpfrag[ks] = pk8(hv);
  }

  // ---- GEMM2: alpha' = relu(W2' . h1^T + b2'); ex = exp2(alpha')
  // (W2, b2 pre-scaled by log2(e): exp2(relu(log2e*a)) == exp(relu(a)))
  // h1 rows of own band: same-wave producer/consumer -> lgkmcnt only.
  float ex[16];
  {
    f16x8 hfrag[2];
#pragma unroll
    for (int ks = 0; ks < 2; ++ks)
      hfrag[ks] = frag_lds(HP, eloc, ks * 32 + quad * 8);
    __builtin_amdgcn_s_setprio(1);
#pragma unroll
    for (int t = 0; t < 4; ++t) {
      f32x4 acc = {0.f, 0.f, 0.f, 0.f};
#pragma unroll
      for (int ks = 0; ks < 2; ++ks) {
        const f16x8 af = frag_lds(W2, t * 16 + l15, ks * 32 + quad * 8);
        acc = __builtin_amdgcn_mfma_f32_16x16x32_f16(af, hfrag[ks], acc, 0, 0, 0);
      }
      const int ob = t * 16 + quad * 4;
#pragma unroll
      for (int r = 0; r < 4; ++r)
        ex[t * 4 + r] = __builtin_exp2f(fmaxf(acc[r] + b2s[ob + r], 0.f));
    }
    __builtin_amdgcn_s_setprio(0);
  }
  // v gather issued now (global; overlaps B1/stage/B2 latency)
  float vr[16];
#pragma unroll
  for (int t = 0; t < 4; ++t) {
    const f16x4 v4 = *(const f16x4*)(vh + (size_t)s_mine * 64 + t * 16 + quad * 4);
    vr[t * 4 + 0] = (float)v4[0];
    vr[t * 4 + 1] = (float)v4[1];
    vr[t * 4 + 2] = (float)v4[2];
    vr[t * 4 + 3] = (float)v4[3];
  }
  __syncthreads();  // B1: all waves done with W1, W2, h1

  stage_ws(HP, w16 + 6 * 4096, tid);  // PW2 over h1
  __syncthreads();  // B2: PW2 visible

  // ---- GEMM3: delta = relu(PW2 . hp^T + pb2)
  float del[16];
  __builtin_amdgcn_s_setprio(1);
#pragma unroll
  for (int t = 0; t < 4; ++t) {
    f32x4 acc = {0.f, 0.f, 0.f, 0.f};
#pragma unroll
    for (int ks = 0; ks < 2; ++ks) {
      const f16x8 af = frag_lds(HP, t * 16 + l15, ks * 32 + quad * 8);
      acc = __builtin_amdgcn_mfma_f32_16x16x32_f16(af, hpfrag[ks], acc, 0, 0, 0);
    }
    const int ob = t * 16 + quad * 4;
#pragma unroll
    for (int r = 0; r < 4; ++r)
      del[t * 4 + r] = fmaxf(acc[r] + pb2s[ob + r], 0.f);
  }
  __builtin_amdgcn_s_setprio(0);

  // ---- phase 5: (msg, ex) -> pairb f16x2 (region free since B1)
#pragma unroll
  for (int t = 0; t < 4; ++t) {
#pragma unroll
    for (int r = 0; r < 4; ++r) {
      const int o = t * 16 + quad * 4 + r;
      const float e_ = ex[t * 4 + r];
      pairb[o * 64 + psl(eloc, o)] =
          pk2(e_ * (vr[t * 4 + r] + del[t * 4 + r]), e_);
    }
  }
  __syncthreads();  // B3

  // ---- phase 6: segmented reduce over sorted-dst runs, then atomics.
  // fdot2 against (1,0)/(0,1): f16 pair -> f32 accumulate, lossless vs cvt+add
  {
    const int c = tid & 63;
    const int r = tid >> 6;
    const f16x2 c10 = {(_Float16)1.0f, (_Float16)0.0f};
    const f16x2 c01 = {(_Float16)0.0f, (_Float16)1.0f};
    float am = 0.f, ae = 0.f;
    int cur = -1;
#pragma unroll 1
    for (int t2 = 0; t2 < 16; ++t2) {
      const int el = r * 16 + t2;
      const int d = dsts[el];
      if (d != cur) {
        if (cur >= 0) {
          unsafeAtomicAdd(num + (size_t)cur * 64 + c, am);
          unsafeAtomicAdd(den + (size_t)cur * 64 + c, ae);
        }
        cur = d;
        am = 0.f;
        ae = 0.f;
      }
      if (d >= 0) {
        const f16x2 pe = pairb[c * 64 + psl(el, c)];
        am = __builtin_amdgcn_fdot2(pe, c10, am, false);
        ae = __builtin_amdgcn_fdot2(pe, c01, ae, false);
      }
    }
    if (cur >= 0) {
      unsafeAtomicAdd(num + (size_t)cur * 64 + c, am);
      unsafeAtomicAdd(den + (size_t)cur * 64 + c, ae);
    }
  }
}

// ---------------------------------------------------------------------------
// Kernel C: out = relu((num/(den+1e-16)) @ W_out.T + b_out), MFMA f16.
// ---------------------------------------------------------------------------
__global__ __launch_bounds__(256, 4) void out_proj(
    const float* __restrict__ num, const float* __restrict__ den,
    const _Float16* __restrict__ w16, const float* __restrict__ b_out,
    float* __restrict__ out) {
  __shared__ __align__(16) _Float16 wlds[4608];
  __shared__ float biasv[64];

  const int tid = threadIdx.x;
  const int nb = blockIdx.x * 64;
  const int l15 = tid & 15;
  const int quad = (tid >> 4) & 3;
  const int wband = tid >> 6;
  const int gn = nb + wband * 16 + l15;

  stage_w(wlds, w16 + 7 * 4096, tid);
  if (tid < 64) biasv[tid] = b_out[tid];

  f16x8 bfrag[2];
#pragma unroll
  for (int ks = 0; ks < 2; ++ks) {
    float y[8] = {0.f, 0.f, 0.f, 0.f, 0.f, 0.f, 0.f, 0.f};
    if (gn < NN) {
      const size_t base = (size_t)gn * 64 + ks * 32 + quad * 8;
      const float4 n0 = *(const float4*)(num + base);
      const float4 n1 = *(const float4*)(num + base + 4);
      const float4 d0 = *(const float4*)(den + base);
      const float4 d1 = *(const float4*)(den + base + 4);
      y[0] = n0.x / (d0.x + 1e-16f); y[1] = n0.y / (d0.y + 1e-16f);
      y[2] = n0.z / (d0.z + 1e-16f); y[3] = n0.w / (d0.w + 1e-16f);
      y[4] = n1.x / (d1.x + 1e-16f); y[5] = n1.y / (d1.y + 1e-16f);
      y[6] = n1.z / (d1.z + 1e-16f); y[7] = n1.w / (d1.w + 1e-16f);
    }
    bfrag[ks] = pk8(y);
  }
  __syncthreads();

#pragma unroll
  for (int t = 0; t < 4; ++t) {
    f32x4 acc = {0.f, 0.f, 0.f, 0.f};
#pragma unroll
    for (int ks = 0; ks < 2; ++ks) {
      const f16x8 af = frag_ldh(wlds, t * 16 + l15, ks * 32 + quad * 8);
      acc = __builtin_amdgcn_mfma_f32_16x16x32_f16(af, bfrag[ks], acc, 0, 0, 0);
    }
    if (gn < NN) {
      const int ob = t * 16 + quad * 4;
      float4 r;
      r.x = fmaxf(acc[0] + biasv[ob + 0], 0.f);
      r.y = fmaxf(acc[1] + biasv[ob + 1], 0.f);
      r.z = fmaxf(acc[2] + biasv[ob + 2], 0.f);
      r.w = fmaxf(acc[3] + biasv[ob + 3], 0.f);
      *(float4*)(out + (size_t)gn * 64 + ob) = r;
    }
  }
}

extern "C" void kernel_launch(void* const* d_in, const int* in_sizes, int n_in,
                              void* d_out, int out_size, void* d_ws,
                              size_t ws_size, hipStream_t stream) {
  const float* x      = (const float*)d_in[0];
  const float* pos    = (const float*)d_in[1];
  const int*   ei     = (const int*)d_in[2];
  const float* W_in   = (const float*)d_in[3];
  const float* b_in   = (const float*)d_in[4];
  const float* W_out  = (const float*)d_in[5];
  const float* b_out  = (const float*)d_in[6];
  const float* W_lin  = (const float*)d_in[7];
  const float* W_src  = (const float*)d_in[8];
  const float* W_dst  = (const float*)d_in[9];
  const float* pos_w1 = (const float*)d_in[10];
  const float* pos_b1 = (const float*)d_in[11];
  const float* pos_w2 = (const float*)d_in[12];
  const float* pos_b2 = (const float*)d_in[13];
  const float* att_w1 = (const float*)d_in[14];
  const float* att_b1 = (const float*)d_in[15];
  const float* att_w2 = (const float*)d_in[16];
  const float* att_b2 = (const float*)d_in[17];

  float* ws = (float*)d_ws;
  const size_t NC = (size_t)NN * C;
  float* num = ws;                       // NC f32
  float* den = ws + NC;                  // NC f32
  _Float16* vh = (_Float16*)(ws + 2 * NC);  // NC f16
  _Float16* kh = vh + NC;                    // NC f16
  _Float16* qh = kh + NC;                    // NC f16
  _Float16* w16 = qh + NC;                   // 8*4096 f16
  int* ib     = (int*)(w16 + 8 * 4096);
  int* cnt2   = ib;                      // 8*NN
  int* curs2  = ib + 8 * NN;             // 8*NN
  int* bsum   = ib + 16 * NN;            // NBLK
  int2* srt   = (int2*)(((uintptr_t)(bsum + NBLK) + 15) & ~(uintptr_t)15);

  const dim3 blk(256);
  prep_kernel<<<dim3(64), blk, 0, stream>>>(W_in, W_lin, W_src, W_dst, att_w1,
                                            att_w2, pos_w2, W_out, w16, cnt2);
  node_proj<<<dim3((NN + 63) / 64), blk, 0, stream>>>(x, b_in, w16, ei, cnt2,
                                                      vh, kh, qh);
  scan_partial<<<dim3(NBLK + ZBLK), blk, 0, stream>>>(cnt2, bsum, num);
  scan_final<<<dim3(NBLK), blk, 0, stream>>>(cnt2, bsum, curs2);
  scatter_kernel<<<dim3(NCHUNK), blk, 0, stream>>>(ei, curs2, srt);
  edge_pass<<<dim3((ET + 63) / 64), blk, 0, stream>>>(
      srt, pos, vh, kh, qh, w16, att_b1, att_b2, pos_w1, pos_b1, pos_b2, num,
      den);
  out_proj<<<dim3((NN + 63) / 64), blk, 0, stream>>>(num, den, w16, b_out,
                                                     (float*)d_out);
}

// Round 7
// 308.444 us; speedup vs baseline: 1.5432x; 1.0043x over previous
//
#include <hip/hip_runtime.h>
#include <math.h>

#define NN 50000
#define EE 800000
#define ET (EE + NN)   // 850000 edges incl. self-loops
#define C  64
#define NBLK 49        // ceil(NN/1024) scan blocks
#define NCHUNK 831     // ceil(ET/1024) edge chunks
#define ZBLK 463       // zeroing blocks appended to scan_partial

typedef __attribute__((ext_vector_type(8))) _Float16 f16x8;
typedef __attribute__((ext_vector_type(4))) _Float16 f16x4;
typedef __attribute__((ext_vector_type(2))) _Float16 f16x2;
typedef __attribute__((ext_vector_type(4))) float f32x4;

__device__ __forceinline__ f16x2 pk2(float a, float b) {
  return __builtin_bit_cast(f16x2, __builtin_amdgcn_cvt_pkrtz(a, b));
}
__device__ __forceinline__ f16x4 pk4(float a, float b, float c, float d) {
  return __builtin_shufflevector(pk2(a, b), pk2(c, d), 0, 1, 2, 3);
}
__device__ __forceinline__ f16x8 pk8(const float* y) {
  const f16x4 lo = pk4(y[0], y[1], y[2], y[3]);
  const f16x4 hi = pk4(y[4], y[5], y[6], y[7]);
  return __builtin_shufflevector(lo, hi, 0, 1, 2, 3, 4, 5, 6, 7);
}

// ---------------- padded (stride-72) LDS helpers: node_proj / out_proj ------
__device__ __forceinline__ f16x8 frag_ldh(const _Float16* base, int row,
                                          int kofs) {
  return *(const f16x8*)(base + row * 72 + kofs);
}
__device__ __forceinline__ void stage_w(_Float16* __restrict__ dst,
                                        const _Float16* __restrict__ src16,
                                        int tid) {
  const f16x8* src = (const f16x8*)(src16 + tid * 16);
  _Float16* d = dst + (tid >> 2) * 72 + (tid & 3) * 16;
  ((f16x8*)d)[0] = src[0];
  ((f16x8*)d)[1] = src[1];
}

// ---------------- dense (stride-64) XOR-swizzled LDS helpers: edge_pass -----
// phys byte = row*128 + (colbyte ^ ((row&7)<<4)); bijective per 16B block,
// preserves 16B/8B alignment; 2-way max bank aliasing (free on CDNA4).
__device__ __forceinline__ int swzb(int row, int colbyte) {
  return row * 128 + (colbyte ^ ((row & 7) << 4));
}
__device__ __forceinline__ f16x8 frag_lds(const _Float16* base, int row,
                                          int kofs) {
  return *(const f16x8*)((const char*)base + swzb(row, kofs * 2));
}
__device__ __forceinline__ void stage_ws(_Float16* __restrict__ dst,
                                         const _Float16* __restrict__ src16,
                                         int tid) {
  const f16x8* src = (const f16x8*)(src16 + tid * 16);
  const int row = tid >> 2;
  const int c0 = (tid & 3) * 32;  // bytes
  *(f16x8*)((char*)dst + swzb(row, c0)) = src[0];
  *(f16x8*)((char*)dst + swzb(row, c0 + 16)) = src[1];
}

// pairb swizzle: 2-way banks on BOTH write (vary e,o-quad) and read (vary o)
__device__ __forceinline__ int psl(int e, int o) {
  return (e + 2 * o + (o >> 5)) & 63;
}

// ---------------------------------------------------------------------------
// prep: convert 8 weight matrices f32 -> f16 (blocks 0..7) + zero cnt shards
// order: W_in, W_lin, W_src, W_dst, att_w1, att_w2, pos_w2, W_out
// att_w2 is pre-scaled by log2(e) so edge_pass can use exp2 directly.
// ---------------------------------------------------------------------------
__global__ __launch_bounds__(256) void prep_kernel(
    const float* __restrict__ W_in, const float* __restrict__ W_lin,
    const float* __restrict__ W_src, const float* __restrict__ W_dst,
    const float* __restrict__ att_w1, const float* __restrict__ att_w2,
    const float* __restrict__ pos_w2, const float* __restrict__ W_out,
    _Float16* __restrict__ w16, int* __restrict__ cnt2) {
  if (blockIdx.x < 8) {
    const float* Ws[8] = {W_in, W_lin, W_src, W_dst, att_w1, att_w2, pos_w2,
                          W_out};
    const float* src = Ws[blockIdx.x];
    _Float16* dst = w16 + blockIdx.x * 4096;
    const float sc = (blockIdx.x == 5) ? 1.44269504088896340736f : 1.0f;
#pragma unroll
    for (int i = threadIdx.x * 4; i < 4096; i += 1024) {
      const float4 w = *(const float4*)(src + i);
      *(f16x4*)(dst + i) = pk4(w.x * sc, w.y * sc, w.z * sc, w.w * sc);
    }
  }
  // zero all 8 counter shards (8*NN ints = 2*NN int4) across 64 blocks
  int4* cz = (int4*)cnt2;
#pragma unroll 1
  for (int i = blockIdx.x * 256 + threadIdx.x; i < 2 * NN; i += 64 * 256)
    cz[i] = make_int4(0, 0, 0, 0);
}

// ---------------------------------------------------------------------------
// Scan over sharded counters; extra blocks zero num/den.
// ---------------------------------------------------------------------------
__global__ __launch_bounds__(256) void scan_partial(const int* __restrict__ cnt2,
                                                    int* __restrict__ bsum,
                                                    float* __restrict__ zeroreg) {
  const int t = threadIdx.x;
  if (blockIdx.x >= NBLK) {
    const int zb = blockIdx.x - NBLK;
    float4* dst = (float4*)zeroreg;
    const int total4 = 2 * NN * 64 / 4;
    const float4 z = make_float4(0.f, 0.f, 0.f, 0.f);
#pragma unroll 1
    for (int i = zb * 256 + t; i < total4; i += ZBLK * 256) dst[i] = z;
    return;
  }
  __shared__ int ws[4];
  const int base = blockIdx.x * 1024 + t * 4;
  int s = 0;
  if (base + 3 < NN) {
#pragma unroll
    for (int sh = 0; sh < 8; ++sh) {
      const int4 v = *(const int4*)(cnt2 + sh * NN + base);
      s += v.x + v.y + v.z + v.w;
    }
  } else {
#pragma unroll
    for (int i = 0; i < 4; ++i)
      if (base + i < NN)
#pragma unroll
        for (int sh = 0; sh < 8; ++sh) s += cnt2[sh * NN + base + i];
  }
#pragma unroll
  for (int off = 32; off; off >>= 1) s += __shfl_down(s, off, 64);
  if ((t & 63) == 0) ws[t >> 6] = s;
  __syncthreads();
  if (t == 0) bsum[blockIdx.x] = ws[0] + ws[1] + ws[2] + ws[3];
}

__global__ __launch_bounds__(256) void scan_final(const int* __restrict__ cnt2,
                                                  const int* __restrict__ bsum,
                                                  int* __restrict__ curs2) {
  __shared__ int tsum[256];
  __shared__ int sblk[64];
  const int t = threadIdx.x;
  if (t < 64) {
    const int mine = (t < NBLK) ? bsum[t] : 0;
    int v = mine;
#pragma unroll
    for (int off = 1; off < 64; off <<= 1) {
      const int u = __shfl_up(v, off, 64);
      if (t >= off) v += u;
    }
    sblk[t] = v - mine;
  }
  const int base = blockIdx.x * 1024 + t * 4;
  int c2[8][4];
  int v[4] = {0, 0, 0, 0};
  if (base + 3 < NN) {
#pragma unroll
    for (int sh = 0; sh < 8; ++sh) {
      const int4 x = *(const int4*)(cnt2 + sh * NN + base);
      c2[sh][0] = x.x; c2[sh][1] = x.y; c2[sh][2] = x.z; c2[sh][3] = x.w;
      v[0] += x.x; v[1] += x.y; v[2] += x.z; v[3] += x.w;
    }
  } else {
#pragma unroll
    for (int sh = 0; sh < 8; ++sh)
#pragma unroll
      for (int i = 0; i < 4; ++i) {
        const int c = (base + i < NN) ? cnt2[sh * NN + base + i] : 0;
        c2[sh][i] = c;
        v[i] += c;
      }
  }
  const int s = v[0] + v[1] + v[2] + v[3];
  tsum[t] = s;
  __syncthreads();
  for (int off = 1; off < 256; off <<= 1) {
    const int u = (t >= off) ? tsum[t - off] : 0;
    __syncthreads();
    tsum[t] += u;
    __syncthreads();
  }
  int ex = sblk[blockIdx.x] + tsum[t] - s;
  int offs[8][4];
#pragma unroll
  for (int i = 0; i < 4; ++i) {
    int run = ex;
#pragma unroll
    for (int sh = 0; sh < 8; ++sh) {
      offs[sh][i] = run;
      run += c2[sh][i];
    }
    ex += v[i];
  }
  if (base + 3 < NN) {
#pragma unroll
    for (int sh = 0; sh < 8; ++sh)
      *(int4*)(curs2 + sh * NN + base) =
          make_int4(offs[sh][0], offs[sh][1], offs[sh][2], offs[sh][3]);
  } else {
#pragma unroll
    for (int sh = 0; sh < 8; ++sh)
#pragma unroll
      for (int i = 0; i < 4; ++i)
        if (base + i < NN) curs2[sh * NN + base + i] = offs[sh][i];
  }
}

// scatter: block b owns edge chunk b (1024 edges); shard = b&7 (XCD-aligned).
__global__ __launch_bounds__(256) void scatter_kernel(const int* __restrict__ ei,
                                                      int* __restrict__ curs2,
                                                      int2* __restrict__ srt) {
  const int chunk = blockIdx.x;
  int* cs = curs2 + (chunk & 7) * NN;
  const int e0 = chunk * 1024 + threadIdx.x * 4;
  if (e0 >= ET) return;
  int s[4], d[4];
  if (e0 + 3 < EE) {
    const int4 sv = *(const int4*)(ei + e0);
    const int4 dv = *(const int4*)(ei + EE + e0);
    s[0] = sv.x; s[1] = sv.y; s[2] = sv.z; s[3] = sv.w;
    d[0] = dv.x; d[1] = dv.y; d[2] = dv.z; d[3] = dv.w;
  } else {
#pragma unroll
    for (int i = 0; i < 4; ++i) {
      const int e = e0 + i;
      if (e < EE) {
        s[i] = ei[e];
        d[i] = ei[EE + e];
      } else if (e < ET) {
        s[i] = d[i] = e - EE;
      } else {
        s[i] = d[i] = -1;
      }
    }
  }
#pragma unroll
  for (int i = 0; i < 4; ++i) {
    if (d[i] >= 0) {
      const int p = atomicAdd(&cs[d[i]], 1);
      srt[p] = make_int2(s[i], d[i]);
    }
  }
}

// ---------------------------------------------------------------------------
// Kernel A: fused sharded histogram + node projections (MFMA f16).
// ---------------------------------------------------------------------------
__global__ __launch_bounds__(256, 3) void node_proj(
    const float* __restrict__ x, const float* __restrict__ b_in,
    const _Float16* __restrict__ w16, const int* __restrict__ ei,
    int* __restrict__ cnt2, _Float16* __restrict__ vh,
    _Float16* __restrict__ kh, _Float16* __restrict__ qh) {
  __shared__ __align__(16) _Float16 wlds[4 * 4608];  // W_in|W_lin|W_src|W_dst
  __shared__ __align__(16) _Float16 hlds[4608];
  __shared__ float biasv[64];

  const int tid = threadIdx.x;
  const int nb = blockIdx.x * 64;
  const int l15 = tid & 15;
  const int quad = (tid >> 4) & 3;
  const int wband = tid >> 6;
  const int nloc = wband * 16 + l15;
  const int gn = nb + nloc;

  // sharded fire-and-forget histogram; chunk c = edges [c*1024,(c+1)*1024)
#pragma unroll 1
  for (int chunk = blockIdx.x; chunk < NCHUNK; chunk += gridDim.x) {
    int* cs = cnt2 + (chunk & 7) * NN;
    const int e0 = chunk * 1024 + tid * 4;
    if (e0 < ET) {
      int d[4];
      if (e0 + 3 < EE) {
        const int4 dv = *(const int4*)(ei + EE + e0);
        d[0] = dv.x; d[1] = dv.y; d[2] = dv.z; d[3] = dv.w;
      } else {
#pragma unroll
        for (int i = 0; i < 4; ++i) {
          const int e = e0 + i;
          d[i] = (e < EE) ? ei[EE + e] : ((e < ET) ? e - EE : -1);
        }
      }
#pragma unroll
      for (int i = 0; i < 4; ++i)
        if (d[i] >= 0) atomicAdd(&cs[d[i]], 1);
    }
  }

#pragma unroll
  for (int w = 0; w < 4; ++w) stage_w(wlds + w * 4608, w16 + w * 4096, tid);
  if (tid < 64) biasv[tid] = b_in[tid];

  // B-frag from x (f32 -> f16)
  f16x8 bfrag[2];
#pragma unroll
  for (int ks = 0; ks < 2; ++ks) {
    float y[8] = {0.f, 0.f, 0.f, 0.f, 0.f, 0.f, 0.f, 0.f};
    if (gn < NN) {
      const float4 a = *(const float4*)(x + (size_t)gn * 64 + ks * 32 + quad * 8);
      const float4 b = *(const float4*)(x + (size_t)gn * 64 + ks * 32 + quad * 8 + 4);
      y[0] = a.x; y[1] = a.y; y[2] = a.z; y[3] = a.w;
      y[4] = b.x; y[5] = b.y; y[6] = b.z; y[7] = b.w;
    }
    bfrag[ks] = pk8(y);
  }
  __syncthreads();  // B0

  // GEMM1: h = relu(W_in . x^T + b) -> hlds rows [n][o] f16
#pragma unroll
  for (int t = 0; t < 4; ++t) {
    f32x4 acc = {0.f, 0.f, 0.f, 0.f};
#pragma unroll
    for (int ks = 0; ks < 2; ++ks) {
      const f16x8 af = frag_ldh(wlds, t * 16 + l15, ks * 32 + quad * 8);
      acc = __builtin_amdgcn_mfma_f32_16x16x32_f16(af, bfrag[ks], acc, 0, 0, 0);
    }
    const int hb = t * 16 + quad * 4;
    *(f16x4*)(hlds + nloc * 72 + hb) =
        pk4(fmaxf(acc[0] + biasv[hb + 0], 0.f), fmaxf(acc[1] + biasv[hb + 1], 0.f),
            fmaxf(acc[2] + biasv[hb + 2], 0.f), fmaxf(acc[3] + biasv[hb + 3], 0.f));
  }
  __syncthreads();  // B1

  f16x8 hfrag[2];
#pragma unroll
  for (int ks = 0; ks < 2; ++ks)
    hfrag[ks] = frag_ldh(hlds, nloc, ks * 32 + quad * 8);

  _Float16* outs[3] = {vh, kh, qh};
#pragma unroll
  for (int p = 0; p < 3; ++p) {
    const _Float16* W = wlds + (p + 1) * 4608;
#pragma unroll
    for (int t = 0; t < 4; ++t) {
      f32x4 acc = {0.f, 0.f, 0.f, 0.f};
#pragma unroll
      for (int ks = 0; ks < 2; ++ks) {
        const f16x8 af = frag_ldh(W, t * 16 + l15, ks * 32 + quad * 8);
        acc = __builtin_amdgcn_mfma_f32_16x16x32_f16(af, hfrag[ks], acc, 0, 0, 0);
      }
      if (gn < NN) {
        *(f16x4*)(outs[p] + (size_t)gn * 64 + t * 16 + quad * 4) =
            pk4(acc[0], acc[1], acc[2], acc[3]);
      }
    }
  }
}

// ---------------------------------------------------------------------------
// Kernel B: MFMA (f16) edge pass. R2 pipeline, LDS lifetime-folded:
//   region A (8KB): W1 -> h1 -> PW2   region B (8KB): W2
//   pairb (16KB) aliases A|B after all GEMMs done.
// Static LDS 18.0KiB (granule-safe) -> 8 blocks/CU, 32 waves (100% theor).
// Cost: 2 extra barriers (B1a: W1 dead before h1 overwrite; B3: PW2 dead
// before pairb overwrite). Zero arithmetic changes vs R2.
// ---------------------------------------------------------------------------
__global__ __launch_bounds__(256, 8) void edge_pass(
    const int2* __restrict__ srt, const float* __restrict__ pos,
    const _Float16* __restrict__ vh, const _Float16* __restrict__ kh,
    const _Float16* __restrict__ qh, const _Float16* __restrict__ w16,
    const float* __restrict__ att_b1, const float* __restrict__ att_b2,
    const float* __restrict__ pos_w1, const float* __restrict__ pos_b1,
    const float* __restrict__ pos_b2, float* __restrict__ num,
    float* __restrict__ den) {
  __shared__ __align__(16) _Float16 smem[8192];  // A(4096h) | B(4096h)
  __shared__ __align__(16) float posw1T[3 * 64];
  __shared__ float b1s[64], b2s[64], pb1s[64], pb2s[64];
  __shared__ int dsts[64];

  _Float16* WA = smem;            // W1, then h1, then PW2
  _Float16* W2 = smem + 4096;
  f16x2* pairb = (f16x2*)smem;    // 64ch x 64slot = 16KB, aliases A|B

  const int tid = threadIdx.x;
  const int eb = blockIdx.x * 64;
  const int l15 = tid & 15;
  const int quad = (tid >> 4) & 3;
  const int wband = tid >> 6;
  const int eloc = wband * 16 + l15;

  // ---- phase 0a: per-lane edge read + B-frag: ad = q[dst]-k[src] (f16)
  int s_mine, d_mine;
  f16x8 bfrag[2];
  float dp0, dp1, dp2;
  {
    const int e = eb + eloc;
    int2 sd = make_int2(0, 0);
    int valid_d = -1;
    if (e < ET) {
      sd = srt[e];
      valid_d = sd.y;
    }
    s_mine = sd.x;
    d_mine = sd.y;
    if (quad == 0) dsts[eloc] = valid_d;
#pragma unroll
    for (int ks = 0; ks < 2; ++ks) {
      const f16x8 qv =
          *(const f16x8*)(qh + (size_t)d_mine * 64 + ks * 32 + quad * 8);
      const f16x8 kv =
          *(const f16x8*)(kh + (size_t)s_mine * 64 + ks * 32 + quad * 8);
      bfrag[ks] = qv - kv;
    }
    dp0 = pos[(size_t)d_mine * 3 + 0] - pos[(size_t)s_mine * 3 + 0];
    dp1 = pos[(size_t)d_mine * 3 + 1] - pos[(size_t)s_mine * 3 + 1];
    dp2 = pos[(size_t)d_mine * 3 + 2] - pos[(size_t)s_mine * 3 + 2];
  }

  // ---- phase 0b: stage W1 (region A), W2 (region B), biases, posw1T
  stage_ws(WA, w16 + 4 * 4096, tid);
  stage_ws(W2, w16 + 5 * 4096, tid);
  if (tid < 64) {
    b1s[tid] = att_b1[tid];
    b2s[tid] = att_b2[tid] * 1.44269504088896340736f;  // W2 prescaled in prep
    pb1s[tid] = pos_b1[tid];
    pb2s[tid] = pos_b2[tid];
    posw1T[0 * 64 + tid] = pos_w1[tid * 3 + 0];
    posw1T[1 * 64 + tid] = pos_w1[tid * 3 + 1];
    posw1T[2 * 64 + tid] = pos_w1[tid * 3 + 2];
  }
  __syncthreads();  // B0

  // ---- GEMM1: h1 = relu(W1 . ad^T + b1) -> packed regs (ph[t])
  f16x4 ph[4];
#pragma unroll
  for (int t = 0; t < 4; ++t) {
    f32x4 acc = {0.f, 0.f, 0.f, 0.f};
#pragma unroll
    for (int ks = 0; ks < 2; ++ks) {
      const f16x8 af = frag_lds(WA, t * 16 + l15, ks * 32 + quad * 8);
      acc = __builtin_amdgcn_mfma_f32_16x16x32_f16(af, bfrag[ks], acc, 0, 0, 0);
    }
    const int hb = t * 16 + quad * 4;
    ph[t] =
        pk4(fmaxf(acc[0] + b1s[hb + 0], 0.f), fmaxf(acc[1] + b1s[hb + 1], 0.f),
            fmaxf(acc[2] + b1s[hb + 2], 0.f), fmaxf(acc[3] + b1s[hb + 3], 0.f));
  }
  __syncthreads();  // B1a: all waves done reading W1 -> region A reusable

  // write h1 rows (own band only; wave-private) into region A
#pragma unroll
  for (int t = 0; t < 4; ++t)
    *(f16x4*)((char*)WA + swzb(eloc, (t * 16 + quad * 4) * 2)) = ph[t];

  // ---- hp in registers (k=3 pos-MLP layer 1 for this lane's 16 k-values)
  f16x8 hpfrag[2];
#pragma unroll
  for (int ks = 0; ks < 2; ++ks) {
    float hv[8];
#pragma unroll
    for (int j = 0; j < 8; ++j) {
      const int i = ks * 32 + quad * 8 + j;
      float h = pb1s[i];
      h = fmaf(dp0, posw1T[i], h);
      h = fmaf(dp1, posw1T[64 + i], h);
      h = fmaf(dp2, posw1T[128 + i], h);
      hv[j] = fmaxf(h, 0.f);
    }
    hpfrag[ks] = pk8(hv);
  }

  // ---- GEMM2: alpha' = relu(W2' . h1^T + b2'); ex = exp2(alpha')
  // (W2, b2 pre-scaled by log2(e): exp2(relu(log2e*a)) == exp(relu(a)))
  // h1 rows of own band: same-wave producer/consumer -> lgkmcnt only.
  float ex[16];
  {
    f16x8 hfrag[2];
#pragma unroll
    for (int ks = 0; ks < 2; ++ks)
      hfrag[ks] = frag_lds(WA, eloc, ks * 32 + quad * 8);
#pragma unroll
    for (int t = 0; t < 4; ++t) {
      f32x4 acc = {0.f, 0.f, 0.f, 0.f};
#pragma unroll
      for (int ks = 0; ks < 2; ++ks) {
        const f16x8 af = frag_lds(W2, t * 16 + l15, ks * 32 + quad * 8);
        acc = __builtin_amdgcn_mfma_f32_16x16x32_f16(af, hfrag[ks], acc, 0, 0, 0);
      }
      const int ob = t * 16 + quad * 4;
#pragma unroll
      for (int r = 0; r < 4; ++r)
        ex[t * 4 + r] = __builtin_exp2f(fmaxf(acc[r] + b2s[ob + r], 0.f));
    }
  }
  // v gather issued now (global; overlaps B1/stage/B2 latency)
  float vr[16];
#pragma unroll
  for (int t = 0; t < 4; ++t) {
    const f16x4 v4 = *(const f16x4*)(vh + (size_t)s_mine * 64 + t * 16 + quad * 4);
    vr[t * 4 + 0] = (float)v4[0];
    vr[t * 4 + 1] = (float)v4[1];
    vr[t * 4 + 2] = (float)v4[2];
    vr[t * 4 + 3] = (float)v4[3];
  }
  __syncthreads();  // B1b: all waves done with h1 (A) and W2 (B)

  stage_ws(WA, w16 + 6 * 4096, tid);  // PW2 over region A
  __syncthreads();  // B2: PW2 visible

  // ---- GEMM3: delta = relu(PW2 . hp^T + pb2)
  float del[16];
#pragma unroll
  for (int t = 0; t < 4; ++t) {
    f32x4 acc = {0.f, 0.f, 0.f, 0.f};
#pragma unroll
    for (int ks = 0; ks < 2; ++ks) {
      const f16x8 af = frag_lds(WA, t * 16 + l15, ks * 32 + quad * 8);
      acc = __builtin_amdgcn_mfma_f32_16x16x32_f16(af, hpfrag[ks], acc, 0, 0, 0);
    }
    const int ob = t * 16 + quad * 4;
#pragma unroll
    for (int r = 0; r < 4; ++r)
      del[t * 4 + r] = fmaxf(acc[r] + pb2s[ob + r], 0.f);
  }
  __syncthreads();  // B3: all waves done reading PW2 -> smem fully dead

  // ---- phase 5: (msg, ex) -> pairb f16x2 (over A|B)
#pragma unroll
  for (int t = 0; t < 4; ++t) {
#pragma unroll
    for (int r = 0; r < 4; ++r) {
      const int o = t * 16 + quad * 4 + r;
      const float e_ = ex[t * 4 + r];
      pairb[o * 64 + psl(eloc, o)] =
          pk2(e_ * (vr[t * 4 + r] + del[t * 4 + r]), e_);
    }
  }
  __syncthreads();  // B4

  // ---- phase 6: segmented reduce over sorted-dst runs, then atomics
  {
    const int c = tid & 63;
    const int r = tid >> 6;
    float am = 0.f, ae = 0.f;
    int cur = -1;
#pragma unroll 1
    for (int t2 = 0; t2 < 16; ++t2) {
      const int el = r * 16 + t2;
      const int d = dsts[el];
      if (d != cur) {
        if (cur >= 0) {
          unsafeAtomicAdd(num + (size_t)cur * 64 + c, am);
          unsafeAtomicAdd(den + (size_t)cur * 64 + c, ae);
        }
        cur = d;
        am = 0.f;
        ae = 0.f;
      }
      if (d >= 0) {
        const f16x2 pe = pairb[c * 64 + psl(el, c)];
        am += (float)pe[0];
        ae += (float)pe[1];
      }
    }
    if (cur >= 0) {
      unsafeAtomicAdd(num + (size_t)cur * 64 + c, am);
      unsafeAtomicAdd(den + (size_t)cur * 64 + c, ae);
    }
  }
}

// ---------------------------------------------------------------------------
// Kernel C: out = relu((num/(den+1e-16)) @ W_out.T + b_out), MFMA f16.
// ---------------------------------------------------------------------------
__global__ __launch_bounds__(256, 4) void out_proj(
    const float* __restrict__ num, const float* __restrict__ den,
    const _Float16* __restrict__ w16, const float* __restrict__ b_out,
    float* __restrict__ out) {
  __shared__ __align__(16) _Float16 wlds[4608];
  __shared__ float biasv[64];

  const int tid = threadIdx.x;
  const int nb = blockIdx.x * 64;
  const int l15 = tid & 15;
  const int quad = (tid >> 4) & 3;
  const int wband = tid >> 6;
  const int gn = nb + wband * 16 + l15;

  stage_w(wlds, w16 + 7 * 4096, tid);
  if (tid < 64) biasv[tid] = b_out[tid];

  f16x8 bfrag[2];
#pragma unroll
  for (int ks = 0; ks < 2; ++ks) {
    float y[8] = {0.f, 0.f, 0.f, 0.f, 0.f, 0.f, 0.f, 0.f};
    if (gn < NN) {
      const size_t base = (size_t)gn * 64 + ks * 32 + quad * 8;
      const float4 n0 = *(const float4*)(num + base);
      const float4 n1 = *(const float4*)(num + base + 4);
      const float4 d0 = *(const float4*)(den + base);
      const float4 d1 = *(const float4*)(den + base + 4);
      y[0] = n0.x / (d0.x + 1e-16f); y[1] = n0.y / (d0.y + 1e-16f);
      y[2] = n0.z / (d0.z + 1e-16f); y[3] = n0.w / (d0.w + 1e-16f);
      y[4] = n1.x / (d1.x + 1e-16f); y[5] = n1.y / (d1.y + 1e-16f);
      y[6] = n1.z / (d1.z + 1e-16f); y[7] = n1.w / (d1.w + 1e-16f);
    }
    bfrag[ks] = pk8(y);
  }
  __syncthreads();

#pragma unroll
  for (int t = 0; t < 4; ++t) {
    f32x4 acc = {0.f, 0.f, 0.f, 0.f};
#pragma unroll
    for (int ks = 0; ks < 2; ++ks) {
      const f16x8 af = frag_ldh(wlds, t * 16 + l15, ks * 32 + quad * 8);
      acc = __builtin_amdgcn_mfma_f32_16x16x32_f16(af, bfrag[ks], acc, 0, 0, 0);
    }
    if (gn < NN) {
      const int ob = t * 16 + quad * 4;
      float4 r;
      r.x = fmaxf(acc[0] + biasv[ob + 0], 0.f);
      r.y = fmaxf(acc[1] + biasv[ob + 1], 0.f);
      r.z = fmaxf(acc[2] + biasv[ob + 2], 0.f);
      r.w = fmaxf(acc[3] + biasv[ob + 3], 0.f);
      *(float4*)(out + (size_t)gn * 64 + ob) = r;
    }
  }
}

extern "C" void kernel_launch(void* const* d_in, const int* in_sizes, int n_in,
                              void* d_out, int out_size, void* d_ws,
                              size_t ws_size, hipStream_t stream) {
  const float* x      = (const float*)d_in[0];
  const float* pos    = (const float*)d_in[1];
  const int*   ei     = (const int*)d_in[2];
  const float* W_in   = (const float*)d_in[3];
  const float* b_in   = (const float*)d_in[4];
  const float* W_out  = (const float*)d_in[5];
  const float* b_out  = (const float*)d_in[6];
  const float* W_lin  = (const float*)d_in[7];
  const float* W_src  = (const float*)d_in[8];
  const float* W_dst  = (const float*)d_in[9];
  const float* pos_w1 = (const float*)d_in[10];
  const float* pos_b1 = (const float*)d_in[11];
  const float* pos_w2 = (const float*)d_in[12];
  const float* pos_b2 = (const float*)d_in[13];
  const float* att_w1 = (const float*)d_in[14];
  const float* att_b1 = (const float*)d_in[15];
  const float* att_w2 = (const float*)d_in[16];
  const float* att_b2 = (const float*)d_in[17];

  float* ws = (float*)d_ws;
  const size_t NC = (size_t)NN * C;
  float* num = ws;                       // NC f32
  float* den = ws + NC;                  // NC f32
  _Float16* vh = (_Float16*)(ws + 2 * NC);  // NC f16
  _Float16* kh = vh + NC;                    // NC f16
  _Float16* qh = kh + NC;                    // NC f16
  _Float16* w16 = qh + NC;                   // 8*4096 f16
  int* ib     = (int*)(w16 + 8 * 4096);
  int* cnt2   = ib;                      // 8*NN
  int* curs2  = ib + 8 * NN;             // 8*NN
  int* bsum   = ib + 16 * NN;            // NBLK
  int2* srt   = (int2*)(((uintptr_t)(bsum + NBLK) + 15) & ~(uintptr_t)15);

  const dim3 blk(256);
  prep_kernel<<<dim3(64), blk, 0, stream>>>(W_in, W_lin, W_src, W_dst, att_w1,
                                            att_w2, pos_w2, W_out, w16, cnt2);
  node_proj<<<dim3((NN + 63) / 64), blk, 0, stream>>>(x, b_in, w16, ei, cnt2,
                                                      vh, kh, qh);
  scan_partial<<<dim3(NBLK + ZBLK), blk, 0, stream>>>(cnt2, bsum, num);
  scan_final<<<dim3(NBLK), blk, 0, stream>>>(cnt2, bsum, curs2);
  scatter_kernel<<<dim3(NCHUNK), blk, 0, stream>>>(ei, curs2, srt);
  edge_pass<<<dim3((ET + 63) / 64), blk, 0, stream>>>(
      srt, pos, vh, kh, qh, w16, att_b1, att_b2, pos_w1, pos_b1, pos_b2, num,
      den);
  out_proj<<<dim3((NN + 63) / 64), blk, 0, stream>>>(num, den, w16, b_out,
                                                     (float*)d_out);
}

// Round 8
// 293.822 us; speedup vs baseline: 1.6200x; 1.0498x over previous
//
#include <hip/hip_runtime.h>
#include <math.h>

#define NN 50000
#define EE 800000
#define ET (EE + NN)   // 850000 edges incl. self-loops
#define C  64
#define NBLK 49        // ceil(NN/1024) scan blocks
#define NCHUNK 831     // ceil(ET/1024) edge chunks
#define ZBLK 463       // zeroing blocks appended to scan_partial

typedef __attribute__((ext_vector_type(8))) _Float16 f16x8;
typedef __attribute__((ext_vector_type(4))) _Float16 f16x4;
typedef __attribute__((ext_vector_type(2))) _Float16 f16x2;
typedef __attribute__((ext_vector_type(4))) float f32x4;

__device__ __forceinline__ f16x2 pk2(float a, float b) {
  return __builtin_bit_cast(f16x2, __builtin_amdgcn_cvt_pkrtz(a, b));
}
__device__ __forceinline__ f16x4 pk4(float a, float b, float c, float d) {
  return __builtin_shufflevector(pk2(a, b), pk2(c, d), 0, 1, 2, 3);
}
__device__ __forceinline__ f16x8 pk8(const float* y) {
  const f16x4 lo = pk4(y[0], y[1], y[2], y[3]);
  const f16x4 hi = pk4(y[4], y[5], y[6], y[7]);
  return __builtin_shufflevector(lo, hi, 0, 1, 2, 3, 4, 5, 6, 7);
}

// ---------------- padded (stride-72) LDS helpers: node_proj / out_proj ------
__device__ __forceinline__ f16x8 frag_ldh(const _Float16* base, int row,
                                          int kofs) {
  return *(const f16x8*)(base + row * 72 + kofs);
}
__device__ __forceinline__ void stage_w(_Float16* __restrict__ dst,
                                        const _Float16* __restrict__ src16,
                                        int tid) {
  const f16x8* src = (const f16x8*)(src16 + tid * 16);
  _Float16* d = dst + (tid >> 2) * 72 + (tid & 3) * 16;
  ((f16x8*)d)[0] = src[0];
  ((f16x8*)d)[1] = src[1];
}

// ---------------- dense (stride-64) XOR-swizzled LDS helpers: edge_pass -----
// phys byte = row*128 + (colbyte ^ ((row&7)<<4)); bijective per 16B block,
// preserves 16B/8B alignment; 2-way max bank aliasing (free on CDNA4).
__device__ __forceinline__ int swzb(int row, int colbyte) {
  return row * 128 + (colbyte ^ ((row & 7) << 4));
}
__device__ __forceinline__ f16x8 frag_lds(const _Float16* base, int row,
                                          int kofs) {
  return *(const f16x8*)((const char*)base + swzb(row, kofs * 2));
}
__device__ __forceinline__ void stage_ws(_Float16* __restrict__ dst,
                                         const _Float16* __restrict__ src16,
                                         int tid) {
  const f16x8* src = (const f16x8*)(src16 + tid * 16);
  const int row = tid >> 2;
  const int c0 = (tid & 3) * 32;  // bytes
  *(f16x8*)((char*)dst + swzb(row, c0)) = src[0];
  *(f16x8*)((char*)dst + swzb(row, c0 + 16)) = src[1];
}

// pairb swizzle: 2-way banks on BOTH write (vary e,o-quad) and read (vary o)
__device__ __forceinline__ int psl(int e, int o) {
  return (e + 2 * o + (o >> 5)) & 63;
}

// ---------------------------------------------------------------------------
// prep: convert 8 weight matrices f32 -> f16 (blocks 0..7) + zero cnt shards
// order: W_in, W_lin, W_src, W_dst, att_w1, att_w2, pos_w2, W_out
// att_w2 is pre-scaled by log2(e) so edge_pass can use exp2 directly.
// ---------------------------------------------------------------------------
__global__ __launch_bounds__(256) void prep_kernel(
    const float* __restrict__ W_in, const float* __restrict__ W_lin,
    const float* __restrict__ W_src, const float* __restrict__ W_dst,
    const float* __restrict__ att_w1, const float* __restrict__ att_w2,
    const float* __restrict__ pos_w2, const float* __restrict__ W_out,
    _Float16* __restrict__ w16, int* __restrict__ cnt2) {
  if (blockIdx.x < 8) {
    const float* Ws[8] = {W_in, W_lin, W_src, W_dst, att_w1, att_w2, pos_w2,
                          W_out};
    const float* src = Ws[blockIdx.x];
    _Float16* dst = w16 + blockIdx.x * 4096;
    const float sc = (blockIdx.x == 5) ? 1.44269504088896340736f : 1.0f;
#pragma unroll
    for (int i = threadIdx.x * 4; i < 4096; i += 1024) {
      const float4 w = *(const float4*)(src + i);
      *(f16x4*)(dst + i) = pk4(w.x * sc, w.y * sc, w.z * sc, w.w * sc);
    }
  }
  // zero all 8 counter shards (8*NN ints = 2*NN int4) across 64 blocks
  int4* cz = (int4*)cnt2;
#pragma unroll 1
  for (int i = blockIdx.x * 256 + threadIdx.x; i < 2 * NN; i += 64 * 256)
    cz[i] = make_int4(0, 0, 0, 0);
}

// ---------------------------------------------------------------------------
// Scan over sharded counters; extra blocks zero num/den.
// ---------------------------------------------------------------------------
__global__ __launch_bounds__(256) void scan_partial(const int* __restrict__ cnt2,
                                                    int* __restrict__ bsum,
                                                    float* __restrict__ zeroreg) {
  const int t = threadIdx.x;
  if (blockIdx.x >= NBLK) {
    const int zb = blockIdx.x - NBLK;
    float4* dst = (float4*)zeroreg;
    const int total4 = 2 * NN * 64 / 4;
    const float4 z = make_float4(0.f, 0.f, 0.f, 0.f);
#pragma unroll 1
    for (int i = zb * 256 + t; i < total4; i += ZBLK * 256) dst[i] = z;
    return;
  }
  __shared__ int ws[4];
  const int base = blockIdx.x * 1024 + t * 4;
  int s = 0;
  if (base + 3 < NN) {
#pragma unroll
    for (int sh = 0; sh < 8; ++sh) {
      const int4 v = *(const int4*)(cnt2 + sh * NN + base);
      s += v.x + v.y + v.z + v.w;
    }
  } else {
#pragma unroll
    for (int i = 0; i < 4; ++i)
      if (base + i < NN)
#pragma unroll
        for (int sh = 0; sh < 8; ++sh) s += cnt2[sh * NN + base + i];
  }
#pragma unroll
  for (int off = 32; off; off >>= 1) s += __shfl_down(s, off, 64);
  if ((t & 63) == 0) ws[t >> 6] = s;
  __syncthreads();
  if (t == 0) bsum[blockIdx.x] = ws[0] + ws[1] + ws[2] + ws[3];
}

__global__ __launch_bounds__(256) void scan_final(const int* __restrict__ cnt2,
                                                  const int* __restrict__ bsum,
                                                  int* __restrict__ curs2) {
  __shared__ int tsum[256];
  __shared__ int sblk[64];
  const int t = threadIdx.x;
  if (t < 64) {
    const int mine = (t < NBLK) ? bsum[t] : 0;
    int v = mine;
#pragma unroll
    for (int off = 1; off < 64; off <<= 1) {
      const int u = __shfl_up(v, off, 64);
      if (t >= off) v += u;
    }
    sblk[t] = v - mine;
  }
  const int base = blockIdx.x * 1024 + t * 4;
  int c2[8][4];
  int v[4] = {0, 0, 0, 0};
  if (base + 3 < NN) {
#pragma unroll
    for (int sh = 0; sh < 8; ++sh) {
      const int4 x = *(const int4*)(cnt2 + sh * NN + base);
      c2[sh][0] = x.x; c2[sh][1] = x.y; c2[sh][2] = x.z; c2[sh][3] = x.w;
      v[0] += x.x; v[1] += x.y; v[2] += x.z; v[3] += x.w;
    }
  } else {
#pragma unroll
    for (int sh = 0; sh < 8; ++sh)
#pragma unroll
      for (int i = 0; i < 4; ++i) {
        const int c = (base + i < NN) ? cnt2[sh * NN + base + i] : 0;
        c2[sh][i] = c;
        v[i] += c;
      }
  }
  const int s = v[0] + v[1] + v[2] + v[3];
  tsum[t] = s;
  __syncthreads();
  for (int off = 1; off < 256; off <<= 1) {
    const int u = (t >= off) ? tsum[t - off] : 0;
    __syncthreads();
    tsum[t] += u;
    __syncthreads();
  }
  int ex = sblk[blockIdx.x] + tsum[t] - s;
  int offs[8][4];
#pragma unroll
  for (int i = 0; i < 4; ++i) {
    int run = ex;
#pragma unroll
    for (int sh = 0; sh < 8; ++sh) {
      offs[sh][i] = run;
      run += c2[sh][i];
    }
    ex += v[i];
  }
  if (base + 3 < NN) {
#pragma unroll
    for (int sh = 0; sh < 8; ++sh)
      *(int4*)(curs2 + sh * NN + base) =
          make_int4(offs[sh][0], offs[sh][1], offs[sh][2], offs[sh][3]);
  } else {
#pragma unroll
    for (int sh = 0; sh < 8; ++sh)
#pragma unroll
      for (int i = 0; i < 4; ++i)
        if (base + i < NN) curs2[sh * NN + base + i] = offs[sh][i];
  }
}

// scatter: block b owns edge chunk b (1024 edges); shard = b&7 (XCD-aligned).
__global__ __launch_bounds__(256) void scatter_kernel(const int* __restrict__ ei,
                                                      int* __restrict__ curs2,
                                                      int2* __restrict__ srt) {
  const int chunk = blockIdx.x;
  int* cs = curs2 + (chunk & 7) * NN;
  const int e0 = chunk * 1024 + threadIdx.x * 4;
  if (e0 >= ET) return;
  int s[4], d[4];
  if (e0 + 3 < EE) {
    const int4 sv = *(const int4*)(ei + e0);
    const int4 dv = *(const int4*)(ei + EE + e0);
    s[0] = sv.x; s[1] = sv.y; s[2] = sv.z; s[3] = sv.w;
    d[0] = dv.x; d[1] = dv.y; d[2] = dv.z; d[3] = dv.w;
  } else {
#pragma unroll
    for (int i = 0; i < 4; ++i) {
      const int e = e0 + i;
      if (e < EE) {
        s[i] = ei[e];
        d[i] = ei[EE + e];
      } else if (e < ET) {
        s[i] = d[i] = e - EE;
      } else {
        s[i] = d[i] = -1;
      }
    }
  }
#pragma unroll
  for (int i = 0; i < 4; ++i) {
    if (d[i] >= 0) {
      const int p = atomicAdd(&cs[d[i]], 1);
      srt[p] = make_int2(s[i], d[i]);
    }
  }
}

// ---------------------------------------------------------------------------
// Kernel A: fused sharded histogram + node projections (MFMA f16).
// ---------------------------------------------------------------------------
__global__ __launch_bounds__(256, 3) void node_proj(
    const float* __restrict__ x, const float* __restrict__ b_in,
    const _Float16* __restrict__ w16, const int* __restrict__ ei,
    int* __restrict__ cnt2, _Float16* __restrict__ vh,
    _Float16* __restrict__ kh, _Float16* __restrict__ qh) {
  __shared__ __align__(16) _Float16 wlds[4 * 4608];  // W_in|W_lin|W_src|W_dst
  __shared__ __align__(16) _Float16 hlds[4608];
  __shared__ float biasv[64];

  const int tid = threadIdx.x;
  const int nb = blockIdx.x * 64;
  const int l15 = tid & 15;
  const int quad = (tid >> 4) & 3;
  const int wband = tid >> 6;
  const int nloc = wband * 16 + l15;
  const int gn = nb + nloc;

  // sharded fire-and-forget histogram; chunk c = edges [c*1024,(c+1)*1024)
#pragma unroll 1
  for (int chunk = blockIdx.x; chunk < NCHUNK; chunk += gridDim.x) {
    int* cs = cnt2 + (chunk & 7) * NN;
    const int e0 = chunk * 1024 + tid * 4;
    if (e0 < ET) {
      int d[4];
      if (e0 + 3 < EE) {
        const int4 dv = *(const int4*)(ei + EE + e0);
        d[0] = dv.x; d[1] = dv.y; d[2] = dv.z; d[3] = dv.w;
      } else {
#pragma unroll
        for (int i = 0; i < 4; ++i) {
          const int e = e0 + i;
          d[i] = (e < EE) ? ei[EE + e] : ((e < ET) ? e - EE : -1);
        }
      }
#pragma unroll
      for (int i = 0; i < 4; ++i)
        if (d[i] >= 0) atomicAdd(&cs[d[i]], 1);
    }
  }

#pragma unroll
  for (int w = 0; w < 4; ++w) stage_w(wlds + w * 4608, w16 + w * 4096, tid);
  if (tid < 64) biasv[tid] = b_in[tid];

  // B-frag from x (f32 -> f16)
  f16x8 bfrag[2];
#pragma unroll
  for (int ks = 0; ks < 2; ++ks) {
    float y[8] = {0.f, 0.f, 0.f, 0.f, 0.f, 0.f, 0.f, 0.f};
    if (gn < NN) {
      const float4 a = *(const float4*)(x + (size_t)gn * 64 + ks * 32 + quad * 8);
      const float4 b = *(const float4*)(x + (size_t)gn * 64 + ks * 32 + quad * 8 + 4);
      y[0] = a.x; y[1] = a.y; y[2] = a.z; y[3] = a.w;
      y[4] = b.x; y[5] = b.y; y[6] = b.z; y[7] = b.w;
    }
    bfrag[ks] = pk8(y);
  }
  __syncthreads();  // B0

  // GEMM1: h = relu(W_in . x^T + b) -> hlds rows [n][o] f16
#pragma unroll
  for (int t = 0; t < 4; ++t) {
    f32x4 acc = {0.f, 0.f, 0.f, 0.f};
#pragma unroll
    for (int ks = 0; ks < 2; ++ks) {
      const f16x8 af = frag_ldh(wlds, t * 16 + l15, ks * 32 + quad * 8);
      acc = __builtin_amdgcn_mfma_f32_16x16x32_f16(af, bfrag[ks], acc, 0, 0, 0);
    }
    const int hb = t * 16 + quad * 4;
    *(f16x4*)(hlds + nloc * 72 + hb) =
        pk4(fmaxf(acc[0] + biasv[hb + 0], 0.f), fmaxf(acc[1] + biasv[hb + 1], 0.f),
            fmaxf(acc[2] + biasv[hb + 2], 0.f), fmaxf(acc[3] + biasv[hb + 3], 0.f));
  }
  __syncthreads();  // B1

  f16x8 hfrag[2];
#pragma unroll
  for (int ks = 0; ks < 2; ++ks)
    hfrag[ks] = frag_ldh(hlds, nloc, ks * 32 + quad * 8);

  _Float16* outs[3] = {vh, kh, qh};
#pragma unroll
  for (int p = 0; p < 3; ++p) {
    const _Float16* W = wlds + (p + 1) * 4608;
#pragma unroll
    for (int t = 0; t < 4; ++t) {
      f32x4 acc = {0.f, 0.f, 0.f, 0.f};
#pragma unroll
      for (int ks = 0; ks < 2; ++ks) {
        const f16x8 af = frag_ldh(W, t * 16 + l15, ks * 32 + quad * 8);
        acc = __builtin_amdgcn_mfma_f32_16x16x32_f16(af, hfrag[ks], acc, 0, 0, 0);
      }
      if (gn < NN) {
        *(f16x4*)(outs[p] + (size_t)gn * 64 + t * 16 + quad * 4) =
            pk4(acc[0], acc[1], acc[2], acc[3]);
      }
    }
  }
}

// ---------------------------------------------------------------------------
// Kernel B: MFMA (f16) edge pass. R2 pipeline, LDS lifetime-folded:
//   region A (8KB): W1 -> h1 -> PW2   region B (8KB): W2
//   pairb (16KB) aliases A|B after all GEMMs done.
// Static LDS 18.0KiB -> 8 blocks/CU by resources (LDS 147K<160K, VGPR<=64).
// launch_bounds(256,6): min-waves>=8 forces 32 arch VGPRs + spills (R3/R7
// lesson) -- 6 leaves the allocator at its natural ~40-48, spill-free, and
// the HW still co-schedules 8 blocks because resources allow it.
// ---------------------------------------------------------------------------
__global__ __launch_bounds__(256, 6) void edge_pass(
    const int2* __restrict__ srt, const float* __restrict__ pos,
    const _Float16* __restrict__ vh, const _Float16* __restrict__ kh,
    const _Float16* __restrict__ qh, const _Float16* __restrict__ w16,
    const float* __restrict__ att_b1, const float* __restrict__ att_b2,
    const float* __restrict__ pos_w1, const float* __restrict__ pos_b1,
    const float* __restrict__ pos_b2, float* __restrict__ num,
    float* __restrict__ den) {
  __shared__ __align__(16) _Float16 smem[8192];  // A(4096h) | B(4096h)
  __shared__ __align__(16) float posw1T[3 * 64];
  __shared__ float b1s[64], b2s[64], pb1s[64], pb2s[64];
  __shared__ int dsts[64];

  _Float16* WA = smem;            // W1, then h1, then PW2
  _Float16* W2 = smem + 4096;
  f16x2* pairb = (f16x2*)smem;    // 64ch x 64slot = 16KB, aliases A|B

  const int tid = threadIdx.x;
  const int eb = blockIdx.x * 64;
  const int l15 = tid & 15;
  const int quad = (tid >> 4) & 3;
  const int wband = tid >> 6;
  const int eloc = wband * 16 + l15;

  // ---- phase 0a: per-lane edge read + B-frag: ad = q[dst]-k[src] (f16)
  int s_mine, d_mine;
  f16x8 bfrag[2];
  float dp0, dp1, dp2;
  {
    const int e = eb + eloc;
    int2 sd = make_int2(0, 0);
    int valid_d = -1;
    if (e < ET) {
      sd = srt[e];
      valid_d = sd.y;
    }
    s_mine = sd.x;
    d_mine = sd.y;
    if (quad == 0) dsts[eloc] = valid_d;
#pragma unroll
    for (int ks = 0; ks < 2; ++ks) {
      const f16x8 qv =
          *(const f16x8*)(qh + (size_t)d_mine * 64 + ks * 32 + quad * 8);
      const f16x8 kv =
          *(const f16x8*)(kh + (size_t)s_mine * 64 + ks * 32 + quad * 8);
      bfrag[ks] = qv - kv;
    }
    dp0 = pos[(size_t)d_mine * 3 + 0] - pos[(size_t)s_mine * 3 + 0];
    dp1 = pos[(size_t)d_mine * 3 + 1] - pos[(size_t)s_mine * 3 + 1];
    dp2 = pos[(size_t)d_mine * 3 + 2] - pos[(size_t)s_mine * 3 + 2];
  }

  // ---- phase 0b: stage W1 (region A), W2 (region B), biases, posw1T
  stage_ws(WA, w16 + 4 * 4096, tid);
  stage_ws(W2, w16 + 5 * 4096, tid);
  if (tid < 64) {
    b1s[tid] = att_b1[tid];
    b2s[tid] = att_b2[tid] * 1.44269504088896340736f;  // W2 prescaled in prep
    pb1s[tid] = pos_b1[tid];
    pb2s[tid] = pos_b2[tid];
    posw1T[0 * 64 + tid] = pos_w1[tid * 3 + 0];
    posw1T[1 * 64 + tid] = pos_w1[tid * 3 + 1];
    posw1T[2 * 64 + tid] = pos_w1[tid * 3 + 2];
  }
  __syncthreads();  // B0

  // ---- GEMM1: h1 = relu(W1 . ad^T + b1) -> packed regs (ph[t])
  f16x4 ph[4];
#pragma unroll
  for (int t = 0; t < 4; ++t) {
    f32x4 acc = {0.f, 0.f, 0.f, 0.f};
#pragma unroll
    for (int ks = 0; ks < 2; ++ks) {
      const f16x8 af = frag_lds(WA, t * 16 + l15, ks * 32 + quad * 8);
      acc = __builtin_amdgcn_mfma_f32_16x16x32_f16(af, bfrag[ks], acc, 0, 0, 0);
    }
    const int hb = t * 16 + quad * 4;
    ph[t] =
        pk4(fmaxf(acc[0] + b1s[hb + 0], 0.f), fmaxf(acc[1] + b1s[hb + 1], 0.f),
            fmaxf(acc[2] + b1s[hb + 2], 0.f), fmaxf(acc[3] + b1s[hb + 3], 0.f));
  }
  __syncthreads();  // B1a: all waves done reading W1 -> region A reusable

  // write h1 rows (own band only; wave-private) into region A
#pragma unroll
  for (int t = 0; t < 4; ++t)
    *(f16x4*)((char*)WA + swzb(eloc, (t * 16 + quad * 4) * 2)) = ph[t];

  // ---- hp in registers (k=3 pos-MLP layer 1 for this lane's 16 k-values)
  f16x8 hpfrag[2];
#pragma unroll
  for (int ks = 0; ks < 2; ++ks) {
    float hv[8];
#pragma unroll
    for (int j = 0; j < 8; ++j) {
      const int i = ks * 32 + quad * 8 + j;
      float h = pb1s[i];
      h = fmaf(dp0, posw1T[i], h);
      h = fmaf(dp1, posw1T[64 + i], h);
      h = fmaf(dp2, posw1T[128 + i], h);
      hv[j] = fmaxf(h, 0.f);
    }
    hpfrag[ks] = pk8(hv);
  }

  // ---- GEMM2: alpha' = relu(W2' . h1^T + b2'); ex = exp2(alpha')
  // (W2, b2 pre-scaled by log2(e): exp2(relu(log2e*a)) == exp(relu(a)))
  // h1 rows of own band: same-wave producer/consumer -> lgkmcnt only.
  float ex[16];
  {
    f16x8 hfrag[2];
#pragma unroll
    for (int ks = 0; ks < 2; ++ks)
      hfrag[ks] = frag_lds(WA, eloc, ks * 32 + quad * 8);
#pragma unroll
    for (int t = 0; t < 4; ++t) {
      f32x4 acc = {0.f, 0.f, 0.f, 0.f};
#pragma unroll
      for (int ks = 0; ks < 2; ++ks) {
        const f16x8 af = frag_lds(W2, t * 16 + l15, ks * 32 + quad * 8);
        acc = __builtin_amdgcn_mfma_f32_16x16x32_f16(af, hfrag[ks], acc, 0, 0, 0);
      }
      const int ob = t * 16 + quad * 4;
#pragma unroll
      for (int r = 0; r < 4; ++r)
        ex[t * 4 + r] = __builtin_exp2f(fmaxf(acc[r] + b2s[ob + r], 0.f));
    }
  }
  // v gather issued now (global; overlaps B1/stage/B2 latency)
  float vr[16];
#pragma unroll
  for (int t = 0; t < 4; ++t) {
    const f16x4 v4 = *(const f16x4*)(vh + (size_t)s_mine * 64 + t * 16 + quad * 4);
    vr[t * 4 + 0] = (float)v4[0];
    vr[t * 4 + 1] = (float)v4[1];
    vr[t * 4 + 2] = (float)v4[2];
    vr[t * 4 + 3] = (float)v4[3];
  }
  __syncthreads();  // B1b: all waves done with h1 (A) and W2 (B)

  stage_ws(WA, w16 + 6 * 4096, tid);  // PW2 over region A
  __syncthreads();  // B2: PW2 visible

  // ---- GEMM3: delta = relu(PW2 . hp^T + pb2)
  float del[16];
#pragma unroll
  for (int t = 0; t < 4; ++t) {
    f32x4 acc = {0.f, 0.f, 0.f, 0.f};
#pragma unroll
    for (int ks = 0; ks < 2; ++ks) {
      const f16x8 af = frag_lds(WA, t * 16 + l15, ks * 32 + quad * 8);
      acc = __builtin_amdgcn_mfma_f32_16x16x32_f16(af, hpfrag[ks], acc, 0, 0, 0);
    }
    const int ob = t * 16 + quad * 4;
#pragma unroll
    for (int r = 0; r < 4; ++r)
      del[t * 4 + r] = fmaxf(acc[r] + pb2s[ob + r], 0.f);
  }
  __syncthreads();  // B3: all waves done reading PW2 -> smem fully dead

  // ---- phase 5: (msg, ex) -> pairb f16x2 (over A|B)
#pragma unroll
  for (int t = 0; t < 4; ++t) {
#pragma unroll
    for (int r = 0; r < 4; ++r) {
      const int o = t * 16 + quad * 4 + r;
      const float e_ = ex[t * 4 + r];
      pairb[o * 64 + psl(eloc, o)] =
          pk2(e_ * (vr[t * 4 + r] + del[t * 4 + r]), e_);
    }
  }
  __syncthreads();  // B4

  // ---- phase 6: segmented reduce over sorted-dst runs, then atomics
  {
    const int c = tid & 63;
    const int r = tid >> 6;
    float am = 0.f, ae = 0.f;
    int cur = -1;
#pragma unroll 1
    for (int t2 = 0; t2 < 16; ++t2) {
      const int el = r * 16 + t2;
      const int d = dsts[el];
      if (d != cur) {
        if (cur >= 0) {
          unsafeAtomicAdd(num + (size_t)cur * 64 + c, am);
          unsafeAtomicAdd(den + (size_t)cur * 64 + c, ae);
        }
        cur = d;
        am = 0.f;
        ae = 0.f;
      }
      if (d >= 0) {
        const f16x2 pe = pairb[c * 64 + psl(el, c)];
        am += (float)pe[0];
        ae += (float)pe[1];
      }
    }
    if (cur >= 0) {
      unsafeAtomicAdd(num + (size_t)cur * 64 + c, am);
      unsafeAtomicAdd(den + (size_t)cur * 64 + c, ae);
    }
  }
}

// ---------------------------------------------------------------------------
// Kernel C: out = relu((num/(den+1e-16)) @ W_out.T + b_out), MFMA f16.
// ---------------------------------------------------------------------------
__global__ __launch_bounds__(256, 4) void out_proj(
    const float* __restrict__ num, const float* __restrict__ den,
    const _Float16* __restrict__ w16, const float* __restrict__ b_out,
    float* __restrict__ out) {
  __shared__ __align__(16) _Float16 wlds[4608];
  __shared__ float biasv[64];

  const int tid = threadIdx.x;
  const int nb = blockIdx.x * 64;
  const int l15 = tid & 15;
  const int quad = (tid >> 4) & 3;
  const int wband = tid >> 6;
  const int gn = nb + wband * 16 + l15;

  stage_w(wlds, w16 + 7 * 4096, tid);
  if (tid < 64) biasv[tid] = b_out[tid];

  f16x8 bfrag[2];
#pragma unroll
  for (int ks = 0; ks < 2; ++ks) {
    float y[8] = {0.f, 0.f, 0.f, 0.f, 0.f, 0.f, 0.f, 0.f};
    if (gn < NN) {
      const size_t base = (size_t)gn * 64 + ks * 32 + quad * 8;
      const float4 n0 = *(const float4*)(num + base);
      const float4 n1 = *(const float4*)(num + base + 4);
      const float4 d0 = *(const float4*)(den + base);
      const float4 d1 = *(const float4*)(den + base + 4);
      y[0] = n0.x / (d0.x + 1e-16f); y[1] = n0.y / (d0.y + 1e-16f);
      y[2] = n0.z / (d0.z + 1e-16f); y[3] = n0.w / (d0.w + 1e-16f);
      y[4] = n1.x / (d1.x + 1e-16f); y[5] = n1.y / (d1.y + 1e-16f);
      y[6] = n1.z / (d1.z + 1e-16f); y[7] = n1.w / (d1.w + 1e-16f);
    }
    bfrag[ks] = pk8(y);
  }
  __syncthreads();

#pragma unroll
  for (int t = 0; t < 4; ++t) {
    f32x4 acc = {0.f, 0.f, 0.f, 0.f};
#pragma unroll
    for (int ks = 0; ks < 2; ++ks) {
      const f16x8 af = frag_ldh(wlds, t * 16 + l15, ks * 32 + quad * 8);
      acc = __builtin_amdgcn_mfma_f32_16x16x32_f16(af, bfrag[ks], acc, 0, 0, 0);
    }
    if (gn < NN) {
      const int ob = t * 16 + quad * 4;
      float4 r;
      r.x = fmaxf(acc[0] + biasv[ob + 0], 0.f);
      r.y = fmaxf(acc[1] + biasv[ob + 1], 0.f);
      r.z = fmaxf(acc[2] + biasv[ob + 2], 0.f);
      r.w = fmaxf(acc[3] + biasv[ob + 3], 0.f);
      *(float4*)(out + (size_t)gn * 64 + ob) = r;
    }
  }
}

extern "C" void kernel_launch(void* const* d_in, const int* in_sizes, int n_in,
                              void* d_out, int out_size, void* d_ws,
                              size_t ws_size, hipStream_t stream) {
  const float* x      = (const float*)d_in[0];
  const float* pos    = (const float*)d_in[1];
  const int*   ei     = (const int*)d_in[2];
  const float* W_in   = (const float*)d_in[3];
  const float* b_in   = (const float*)d_in[4];
  const float* W_out  = (const float*)d_in[5];
  const float* b_out  = (const float*)d_in[6];
  const float* W_lin  = (const float*)d_in[7];
  const float* W_src  = (const float*)d_in[8];
  const float* W_dst  = (const float*)d_in[9];
  const float* pos_w1 = (const float*)d_in[10];
  const float* pos_b1 = (const float*)d_in[11];
  const float* pos_w2 = (const float*)d_in[12];
  const float* pos_b2 = (const float*)d_in[13];
  const float* att_w1 = (const float*)d_in[14];
  const float* att_b1 = (const float*)d_in[15];
  const float* att_w2 = (const float*)d_in[16];
  const float* att_b2 = (const float*)d_in[17];

  float* ws = (float*)d_ws;
  const size_t NC = (size_t)NN * C;
  float* num = ws;                       // NC f32
  float* den = ws + NC;                  // NC f32
  _Float16* vh = (_Float16*)(ws + 2 * NC);  // NC f16
  _Float16* kh = vh + NC;                    // NC f16
  _Float16* qh = kh + NC;                    // NC f16
  _Float16* w16 = qh + NC;                   // 8*4096 f16
  int* ib     = (int*)(w16 + 8 * 4096);
  int* cnt2   = ib;                      // 8*NN
  int* curs2  = ib + 8 * NN;             // 8*NN
  int* bsum   = ib + 16 * NN;            // NBLK
  int2* srt   = (int2*)(((uintptr_t)(bsum + NBLK) + 15) & ~(uintptr_t)15);

  const dim3 blk(256);
  prep_kernel<<<dim3(64), blk, 0, stream>>>(W_in, W_lin, W_src, W_dst, att_w1,
                                            att_w2, pos_w2, W_out, w16, cnt2);
  node_proj<<<dim3((NN + 63) / 64), blk, 0, stream>>>(x, b_in, w16, ei, cnt2,
                                                      vh, kh, qh);
  scan_partial<<<dim3(NBLK + ZBLK), blk, 0, stream>>>(cnt2, bsum, num);
  scan_final<<<dim3(NBLK), blk, 0, stream>>>(cnt2, bsum, curs2);
  scatter_kernel<<<dim3(NCHUNK), blk, 0, stream>>>(ei, curs2, srt);
  edge_pass<<<dim3((ET + 63) / 64), blk, 0, stream>>>(
      srt, pos, vh, kh, qh, w16, att_b1, att_b2, pos_w1, pos_b1, pos_b2, num,
      den);
  out_proj<<<dim3((NN + 63) / 64), blk, 0, stream>>>(num, den, w16, b_out,
                                                     (float*)d_out);
}